// Round 1
// baseline (400.185 us; speedup 1.0000x reference)
//
#include <hip/hip_runtime.h>

#define BB 8
#define CC 384
#define NPIX 1024
#define TOTCH 176      // 64 q + 16 k + 96 v
#define BN_EPS 1e-5f

// ws layout (floats):
// qkv  [B][176][N]  @ 0         (1441792)
// sA   [176]        @ 1441792
// sB   [176]        @ 1441968
// ksm  [B][16][N]   @ 1442144   (131072)
// qt   [B][N][64]   @ 1573216   (524288)
// vt   [B][N][96]   @ 2097504   (786432)
// lc   [B][16][96]  @ 2883936   (12288)
// total 2896224 floats = 11.6 MB

// ---------------- K1: q/k/v projection (1x1 conv == per-pixel matmul) -------
__global__ __launch_bounds__(256) void k_proj(const float* __restrict__ x,
    const float* __restrict__ Wq, const float* __restrict__ Wk,
    const float* __restrict__ Wv, float* __restrict__ qkv)
{
    int tid = threadIdx.x;
    int n  = blockIdx.x * 256 + tid;
    int r0 = blockIdx.y * 8;
    int b  = blockIdx.z;
    const float* Wb; int rb;
    if (r0 < 64)      { Wb = Wq; rb = r0; }
    else if (r0 < 80) { Wb = Wk; rb = r0 - 64; }
    else              { Wb = Wv; rb = r0 - 80; }
    const float* xp = x + (size_t)b * CC * NPIX + n;
    const float* wp = Wb + (size_t)rb * CC;
    float acc[8] = {0.f,0.f,0.f,0.f,0.f,0.f,0.f,0.f};
    #pragma unroll 4
    for (int c = 0; c < CC; ++c) {
        float xv = xp[(size_t)c * NPIX];
        #pragma unroll
        for (int r = 0; r < 8; ++r) acc[r] += wp[r * CC + c] * xv;
    }
    float* qp = qkv + ((size_t)b * TOTCH + r0) * NPIX + n;
    #pragma unroll
    for (int r = 0; r < 8; ++r) qp[(size_t)r * NPIX] = acc[r];
}

// ---------------- K2: BN stats -> per-channel scale/bias --------------------
__global__ __launch_bounds__(256) void k_bnstats(const float* __restrict__ qkv,
    const float* __restrict__ gq, const float* __restrict__ bq,
    const float* __restrict__ gv, const float* __restrict__ bv,
    float* __restrict__ sA, float* __restrict__ sB)
{
    int ch = blockIdx.x;
    int row; float gamma, beta;
    if (ch < 64) { row = ch;            gamma = gq[ch];      beta = bq[ch]; }
    else         { int j = ch - 64; row = 80 + j; gamma = gv[j]; beta = bv[j]; }
    int tid = threadIdx.x;
    float s = 0.f, ss = 0.f;
    for (int i = tid; i < BB * NPIX; i += 256) {
        int b = i >> 10, n = i & 1023;
        float val = qkv[((size_t)b * TOTCH + row) * NPIX + n];
        s += val; ss += val * val;
    }
    #pragma unroll
    for (int off = 32; off > 0; off >>= 1) {
        s  += __shfl_down(s, off);
        ss += __shfl_down(ss, off);
    }
    __shared__ float rs[4], rss[4];
    int wid = tid >> 6, lane = tid & 63;
    if (lane == 0) { rs[wid] = s; rss[wid] = ss; }
    __syncthreads();
    if (tid == 0) {
        float S  = rs[0] + rs[1] + rs[2] + rs[3];
        float SS = rss[0] + rss[1] + rss[2] + rss[3];
        float inv = 1.f / (BB * NPIX);
        float mean = S * inv;
        float var  = SS * inv - mean * mean;
        float a = gamma * rsqrtf(var + BN_EPS);
        sA[row] = a;
        sB[row] = beta - mean * a;
    }
}

// ---------------- K3: softmax over N for each (b, key-channel) --------------
__global__ __launch_bounds__(256) void k_softmax(const float* __restrict__ qkv,
                                                 float* __restrict__ ksm)
{
    int kc = blockIdx.x, b = blockIdx.y, tid = threadIdx.x;
    const float* rowp = qkv + ((size_t)b * TOTCH + 64 + kc) * NPIX;
    float v[4];
    #pragma unroll
    for (int j = 0; j < 4; ++j) v[j] = rowp[tid + 256 * j];
    float mx = fmaxf(fmaxf(v[0], v[1]), fmaxf(v[2], v[3]));
    #pragma unroll
    for (int off = 32; off > 0; off >>= 1) mx = fmaxf(mx, __shfl_down(mx, off));
    __shared__ float sm[4], ssum[4];
    int wid = tid >> 6, lane = tid & 63;
    if (lane == 0) sm[wid] = mx;
    __syncthreads();
    mx = fmaxf(fmaxf(sm[0], sm[1]), fmaxf(sm[2], sm[3]));
    float e[4], s = 0.f;
    #pragma unroll
    for (int j = 0; j < 4; ++j) { e[j] = __expf(v[j] - mx); s += e[j]; }
    #pragma unroll
    for (int off = 32; off > 0; off >>= 1) s += __shfl_down(s, off);
    if (lane == 0) ssum[wid] = s;
    __syncthreads();
    float inv = 1.f / (ssum[0] + ssum[1] + ssum[2] + ssum[3]);
    float* op = ksm + ((size_t)b * 16 + kc) * NPIX;
    #pragma unroll
    for (int j = 0; j < 4; ++j) op[tid + 256 * j] = e[j] * inv;
}

// ---------------- K4: apply BN + transpose to (B,N,ch) layouts --------------
__global__ __launch_bounds__(256) void k_tbn(const float* __restrict__ qkv,
    const float* __restrict__ sA, const float* __restrict__ sB,
    float* __restrict__ qt, float* __restrict__ vt)
{
    int idx = blockIdx.x * 256 + threadIdx.x;   // [0, B*160*N)
    int n = idx & 1023;
    int c = (idx >> 10) % 160;
    int b = idx / (160 * 1024);
    if (c < 64) {
        float val = qkv[((size_t)b * TOTCH + c) * NPIX + n];
        qt[((size_t)b * NPIX + n) * 64 + c] = val * sA[c] + sB[c];
    } else {
        int v = c - 64, row = 80 + v;
        float val = qkv[((size_t)b * TOTCH + row) * NPIX + n];
        vt[((size_t)b * NPIX + n) * 96 + v] = val * sA[row] + sB[row];
    }
}

// ---------------- K5: content lambda  lc[b,k,v] = sum_m ksm*vhat ------------
__global__ __launch_bounds__(256) void k_lambdac(const float* __restrict__ ksm,
    const float* __restrict__ vt, float* __restrict__ lc)
{
    int v = blockIdx.x, b = blockIdx.y, tid = threadIdx.x;
    float acc[16];
    #pragma unroll
    for (int k = 0; k < 16; ++k) acc[k] = 0.f;
    for (int m = tid; m < NPIX; m += 256) {
        float vv = vt[((size_t)b * NPIX + m) * 96 + v];
        #pragma unroll
        for (int k = 0; k < 16; ++k)
            acc[k] += ksm[((size_t)b * 16 + k) * NPIX + m] * vv;
    }
    #pragma unroll
    for (int k = 0; k < 16; ++k) {
        #pragma unroll
        for (int off = 32; off > 0; off >>= 1) acc[k] += __shfl_down(acc[k], off);
    }
    __shared__ float red[16][4];
    int wid = tid >> 6, lane = tid & 63;
    if (lane == 0) {
        #pragma unroll
        for (int k = 0; k < 16; ++k) red[k][wid] = acc[k];
    }
    __syncthreads();
    if (tid < 16)
        lc[((size_t)b * 16 + tid) * 96 + v] =
            red[tid][0] + red[tid][1] + red[tid][2] + red[tid][3];
}

// ---------------- K6: fused position lambda + output ------------------------
// wg = (n-tile of 8, b). S[h][n][m] = sum_k q[h,k,n]*P[n,m,k] in LDS, then
// acc[h][v] += S * vhat[v,m]; epilogue adds content-lambda term.
__global__ __launch_bounds__(256) void k_main(const float* __restrict__ pos,
    const float* __restrict__ qt, const float* __restrict__ vt,
    const float* __restrict__ lc, float* __restrict__ out)
{
    __shared__ float q_s[8][64];          // 2 KB
    __shared__ float lc_s[16 * 96];       // 6 KB
    __shared__ float Ps[8 * 32 * 16];     // 16 KB  [n][m][k]
    __shared__ float Vs[32 * 96];         // 12 KB  [m][v]
    __shared__ float Ss[8 * 32 * 4];      // 4 KB   [n][m][h]
    int tid = threadIdx.x;
    int n0 = blockIdx.x * 8;
    int b  = blockIdx.y;

    {   // stage q (512 f) and lambdac (1536 f), both contiguous
        const float4* src = (const float4*)(qt + ((size_t)b * NPIX + n0) * 64);
        float4* dst = (float4*)q_s;
        if (tid < 128) dst[tid] = src[tid];
        const float4* src2 = (const float4*)(lc + (size_t)b * 16 * 96);
        float4* dst2 = (float4*)lc_s;
        #pragma unroll
        for (int j = 0; j < 2; ++j) {
            int i = tid + 256 * j;
            if (i < 384) dst2[i] = src2[i];
        }
    }
    __syncthreads();

    // S-phase mapping: n = tid>>5, h = (tid>>3)&3, mg = tid&7 (m = mg + 8i)
    int sn = tid >> 5, sh = (tid >> 3) & 3, smg = tid & 7;
    float qr[16];
    #pragma unroll
    for (int k = 0; k < 16; ++k) qr[k] = q_s[sn][sh * 16 + k];

    // SV mapping: vg = tid&31 (v = 3*vg), nn = tid>>5
    int vg = tid & 31, nn = tid >> 5;
    int v = vg * 3;
    float acc[4][3];
    #pragma unroll
    for (int h = 0; h < 4; ++h)
        #pragma unroll
        for (int j = 0; j < 3; ++j) acc[h][j] = 0.f;

    const float4* Psrc = (const float4*)pos;
    const float4* Vsrc = (const float4*)vt;

    for (int mt = 0; mt < 32; ++mt) {
        int m0 = mt * 32;
        __syncthreads();   // prev-tile SV reads done before restaging
        {   // stage Ps: 1024 float4, per-n contiguous (m,k) chunks
            float4* Pd = (float4*)Ps;
            #pragma unroll
            for (int j = 0; j < 4; ++j) {
                int i4 = tid + 256 * j;
                int n = i4 >> 7, r = i4 & 127;
                Pd[i4] = Psrc[(size_t)(n0 + n) * 4096 + m0 * 4 + r];
            }
            // stage Vs: 768 float4 contiguous
            float4* Vd = (float4*)Vs;
            #pragma unroll
            for (int j = 0; j < 3; ++j) {
                int i4 = tid + 256 * j;
                Vd[i4] = Vsrc[((size_t)b * NPIX + m0) * 24 + i4];
            }
        }
        __syncthreads();
        // S compute: 4 values each at m = smg + 8i
        #pragma unroll
        for (int i = 0; i < 4; ++i) {
            int m = smg + 8 * i;
            const float4* pp = (const float4*)&Ps[(sn * 32 + m) * 16];
            float4 p0 = pp[0], p1 = pp[1], p2 = pp[2], p3 = pp[3];
            float s = qr[0]*p0.x + qr[1]*p0.y + qr[2]*p0.z + qr[3]*p0.w
                    + qr[4]*p1.x + qr[5]*p1.y + qr[6]*p1.z + qr[7]*p1.w
                    + qr[8]*p2.x + qr[9]*p2.y + qr[10]*p2.z + qr[11]*p2.w
                    + qr[12]*p3.x + qr[13]*p3.y + qr[14]*p3.z + qr[15]*p3.w;
            Ss[(sn * 32 + m) * 4 + sh] = s;
        }
        __syncthreads();
        // SV accumulate
        #pragma unroll 8
        for (int m = 0; m < 32; ++m) {
            float4 s4 = *(const float4*)&Ss[(nn * 32 + m) * 4];
            float v0 = Vs[m * 96 + v];
            float v1 = Vs[m * 96 + v + 1];
            float v2 = Vs[m * 96 + v + 2];
            acc[0][0] += s4.x * v0; acc[0][1] += s4.x * v1; acc[0][2] += s4.x * v2;
            acc[1][0] += s4.y * v0; acc[1][1] += s4.y * v1; acc[1][2] += s4.y * v2;
            acc[2][0] += s4.z * v0; acc[2][1] += s4.z * v1; acc[2][2] += s4.z * v2;
            acc[3][0] += s4.w * v0; acc[3][1] += s4.w * v1; acc[3][2] += s4.w * v2;
        }
    }

    // epilogue: add content-lambda term, write out[b][h*96+v][n]
    #pragma unroll
    for (int h = 0; h < 4; ++h) {
        #pragma unroll
        for (int j = 0; j < 3; ++j) {
            float y = acc[h][j];
            #pragma unroll
            for (int k = 0; k < 16; ++k)
                y += q_s[nn][h * 16 + k] * lc_s[k * 96 + v + j];
            out[((size_t)b * 384 + h * 96 + v + j) * NPIX + n0 + nn] = y;
        }
    }
}

extern "C" void kernel_launch(void* const* d_in, const int* in_sizes, int n_in,
                              void* d_out, int out_size, void* d_ws, size_t ws_size,
                              hipStream_t stream) {
    const float* x   = (const float*)d_in[0];
    const float* Wq  = (const float*)d_in[1];
    const float* Wk  = (const float*)d_in[2];
    const float* Wv  = (const float*)d_in[3];
    const float* gq  = (const float*)d_in[4];
    const float* bq  = (const float*)d_in[5];
    const float* gv  = (const float*)d_in[6];
    const float* bv  = (const float*)d_in[7];
    const float* pos = (const float*)d_in[8];
    float* out = (float*)d_out;
    float* ws  = (float*)d_ws;

    float* qkv = ws;
    float* sA  = ws + 1441792;
    float* sB  = sA + 176;
    float* ksm = ws + 1442144;
    float* qt  = ws + 1573216;
    float* vt  = ws + 2097504;
    float* lc  = ws + 2883936;

    k_proj<<<dim3(4, 22, 8), dim3(256), 0, stream>>>(x, Wq, Wk, Wv, qkv);
    k_bnstats<<<dim3(160), dim3(256), 0, stream>>>(qkv, gq, bq, gv, bv, sA, sB);
    k_softmax<<<dim3(16, 8), dim3(256), 0, stream>>>(qkv, ksm);
    k_tbn<<<dim3(5120), dim3(256), 0, stream>>>(qkv, sA, sB, qt, vt);
    k_lambdac<<<dim3(96, 8), dim3(256), 0, stream>>>(ksm, vt, lc);
    k_main<<<dim3(128, 8), dim3(256), 0, stream>>>(pos, qt, vt, lc, out);
}

// Round 2
// 260.440 us; speedup vs baseline: 1.5366x; 1.5366x over previous
//
#include <hip/hip_runtime.h>

typedef __attribute__((ext_vector_type(8))) short short8;
typedef __attribute__((ext_vector_type(16))) float floatx16;
typedef __attribute__((ext_vector_type(4))) float floatx4;
typedef unsigned short ushort16_t;
typedef unsigned int uint32;

#define BB 8
#define CC 384
#define NPIX 1024
#define TOTCH 176      // 64 q + 16 k + 96 v
#define BN_EPS 1e-5f

// ---------- helpers ----------
__device__ __forceinline__ ushort16_t f2bf(float x) {
    uint32 u = __float_as_uint(x);
    u += 0x7FFFu + ((u >> 16) & 1u);
    return (ushort16_t)(u >> 16);
}
__device__ __forceinline__ uint32 pk2(float a, float b) {
    uint32 ua = __float_as_uint(a); ua += 0x7FFFu + ((ua >> 16) & 1u);
    uint32 ub = __float_as_uint(b); ub += 0x7FFFu + ((ub >> 16) & 1u);
    return (ua >> 16) | (ub & 0xFFFF0000u);
}
__device__ __forceinline__ void dma16(const ushort16_t* g, ushort16_t* l) {
    __builtin_amdgcn_global_load_lds(
        (const __attribute__((address_space(1))) uint32*)g,
        (__attribute__((address_space(3))) uint32*)l, 16, 0, 0);
}

// ws layout (float units):
// qkv  [B][176][N]        @ 0         (1441792)
// sA   [176]              @ 1441792
// sB   [176]              @ 1441968
// ksm  [B][16][N]         @ 1442144   (131072)
// qt_g bf16 [n][kh2][bh32][8]              @f 1573216 (524288 us = 262144 f)
// vt_g bf16 [b][mt32][vh2][vt3][mq4][v16][8] @f 1835360 (786432 us = 393216 f)
// lc_g bf16 [b][vh2][vt3][mq4][v16][8]     @f 2228576 (24576 us = 12288 f)
// end 2240864 floats (~9 MB)

// ---------------- K1: q/k/v projection -------------------------------------
__global__ __launch_bounds__(256) void k_proj(const float* __restrict__ x,
    const float* __restrict__ Wq, const float* __restrict__ Wk,
    const float* __restrict__ Wv, float* __restrict__ qkv)
{
    int tid = threadIdx.x;
    int n  = blockIdx.x * 256 + tid;
    int rg = blockIdx.y;
    int b  = blockIdx.z;
    const float* Wb; int rb, r0;
    if (rg < 4)       { Wb = Wq; rb = rg * 16;       r0 = rg * 16; }
    else if (rg == 4) { Wb = Wk; rb = 0;             r0 = 64; }
    else              { Wb = Wv; rb = (rg - 5) * 16; r0 = 80 + (rg - 5) * 16; }
    const float* xp = x + (size_t)b * CC * NPIX + n;
    const float* wp = Wb + (size_t)rb * CC;
    float acc[16];
    #pragma unroll
    for (int r = 0; r < 16; ++r) acc[r] = 0.f;
    #pragma unroll 2
    for (int c = 0; c < CC; ++c) {
        float xv = xp[(size_t)c * NPIX];
        #pragma unroll
        for (int r = 0; r < 16; ++r) acc[r] += wp[r * CC + c] * xv;
    }
    float* qp = qkv + ((size_t)b * TOTCH + r0) * NPIX + n;
    #pragma unroll
    for (int r = 0; r < 16; ++r) qp[(size_t)r * NPIX] = acc[r];
}

// ---------------- K2: BN stats + softmax (merged) ---------------------------
__global__ __launch_bounds__(256) void k_bnsm(const float* __restrict__ qkv,
    const float* __restrict__ gq, const float* __restrict__ bq,
    const float* __restrict__ gv, const float* __restrict__ bv,
    float* __restrict__ sA, float* __restrict__ sB, float* __restrict__ ksm)
{
    int bx = blockIdx.x, tid = threadIdx.x;
    int wid = tid >> 6, lane = tid & 63;
    if (bx < 160) {
        int ch = bx;
        int row; float gamma, beta;
        if (ch < 64) { row = ch; gamma = gq[ch]; beta = bq[ch]; }
        else { int j = ch - 64; row = 80 + j; gamma = gv[j]; beta = bv[j]; }
        float s = 0.f, ss = 0.f;
        for (int i = tid; i < BB * NPIX; i += 256) {
            int b = i >> 10, n = i & 1023;
            float val = qkv[((size_t)b * TOTCH + row) * NPIX + n];
            s += val; ss += val * val;
        }
        #pragma unroll
        for (int off = 32; off > 0; off >>= 1) {
            s  += __shfl_down(s, off);
            ss += __shfl_down(ss, off);
        }
        __shared__ float rs[4], rss[4];
        if (lane == 0) { rs[wid] = s; rss[wid] = ss; }
        __syncthreads();
        if (tid == 0) {
            float S  = rs[0] + rs[1] + rs[2] + rs[3];
            float SS = rss[0] + rss[1] + rss[2] + rss[3];
            float inv = 1.f / (BB * NPIX);
            float mean = S * inv;
            float var  = SS * inv - mean * mean;
            float a = gamma * rsqrtf(var + BN_EPS);
            sA[row] = a;
            sB[row] = beta - mean * a;
        }
    } else {
        int idx = bx - 160;
        int kc = idx & 15, b = idx >> 4;
        const float* rowp = qkv + ((size_t)b * TOTCH + 64 + kc) * NPIX;
        float v[4];
        #pragma unroll
        for (int j = 0; j < 4; ++j) v[j] = rowp[tid + 256 * j];
        float mx = fmaxf(fmaxf(v[0], v[1]), fmaxf(v[2], v[3]));
        #pragma unroll
        for (int off = 32; off > 0; off >>= 1) mx = fmaxf(mx, __shfl_down(mx, off));
        __shared__ float sm[4], ssum[4];
        if (lane == 0) sm[wid] = mx;
        __syncthreads();
        mx = fmaxf(fmaxf(sm[0], sm[1]), fmaxf(sm[2], sm[3]));
        float e[4], s = 0.f;
        #pragma unroll
        for (int j = 0; j < 4; ++j) { e[j] = __expf(v[j] - mx); s += e[j]; }
        #pragma unroll
        for (int off = 32; off > 0; off >>= 1) s += __shfl_down(s, off);
        if (lane == 0) ssum[wid] = s;
        __syncthreads();
        float inv = 1.f / (ssum[0] + ssum[1] + ssum[2] + ssum[3]);
        float* op = ksm + ((size_t)b * 16 + kc) * NPIX;
        #pragma unroll
        for (int j = 0; j < 4; ++j) op[tid + 256 * j] = e[j] * inv;
    }
}

// ---------------- K3: pack q-hat / v-hat into tiled bf16 buffers ------------
__global__ __launch_bounds__(512) void k_pack(const float* __restrict__ qkv,
    const float* __restrict__ sA, const float* __restrict__ sB,
    ushort16_t* __restrict__ qt_g, ushort16_t* __restrict__ vt_g)
{
    int bx = blockIdx.x, t = threadIdx.x;
    if (bx < 16) {
        // q part: qt_g[n][kh][bh][8]
        int n = bx * 64 + (t & 63);
        int bh0 = t >> 6;
        #pragma unroll
        for (int i = 0; i < 4; ++i) {
            int bh = bh0 * 4 + i;
            int b = bh >> 2, h = bh & 3;
            float vals[16];
            #pragma unroll
            for (int k = 0; k < 16; ++k) {
                int ch = h * 16 + k;
                vals[k] = qkv[((size_t)b * TOTCH + ch) * NPIX + n] * sA[ch] + sB[ch];
            }
            uint4 w0, w1;
            w0.x = pk2(vals[0], vals[1]);  w0.y = pk2(vals[2], vals[3]);
            w0.z = pk2(vals[4], vals[5]);  w0.w = pk2(vals[6], vals[7]);
            w1.x = pk2(vals[8], vals[9]);  w1.y = pk2(vals[10], vals[11]);
            w1.z = pk2(vals[12], vals[13]); w1.w = pk2(vals[14], vals[15]);
            *(uint4*)&qt_g[(size_t)n * 512 + bh * 8]       = w0;
            *(uint4*)&qt_g[(size_t)n * 512 + 256 + bh * 8] = w1;
        }
    } else {
        // v part: vt_g[b][mt][vh][vt][mq][vl][8]
        int gi = (bx - 16) * 512 + t;   // < 98304
        int m8 = gi & 127;
        int vg = (gi >> 7) % 96;
        int b  = gi / (96 * 128);
        int m  = m8 * 8;
        int row = 80 + vg;
        float a = sA[row], bb = sB[row];
        const float* p = qkv + ((size_t)b * TOTCH + row) * NPIX + m;
        float4 f0 = *(const float4*)p;
        float4 f1 = *(const float4*)(p + 4);
        uint4 w;
        w.x = pk2(f0.x * a + bb, f0.y * a + bb);
        w.y = pk2(f0.z * a + bb, f0.w * a + bb);
        w.z = pk2(f1.x * a + bb, f1.y * a + bb);
        w.w = pk2(f1.z * a + bb, f1.w * a + bb);
        int mt = m >> 5, mq = (m >> 3) & 3;
        int vhh = vg / 48, vtt = (vg % 48) >> 4, vl = vg & 15;
        size_t idx = ((((size_t)b * 32 + mt) * 2 + vhh) * 3 + vtt) * 512
                   + mq * 128 + vl * 8;
        *(uint4*)&vt_g[idx] = w;
    }
}

// ---------------- K4: content lambda -> tiled bf16 lc_g ---------------------
__global__ __launch_bounds__(256) void k_lambdac(const float* __restrict__ ksm,
    const float* __restrict__ qkv, const float* __restrict__ sA,
    const float* __restrict__ sB, ushort16_t* __restrict__ lc_g)
{
    int v = blockIdx.x, b = blockIdx.y, tid = threadIdx.x;
    int row = 80 + v;
    float a = sA[row], bb = sB[row];
    const float* vp = qkv + ((size_t)b * TOTCH + row) * NPIX;
    const float* kp = ksm + (size_t)b * 16 * NPIX;
    float acc[16];
    #pragma unroll
    for (int k = 0; k < 16; ++k) acc[k] = 0.f;
    for (int m = tid; m < NPIX; m += 256) {
        float vv = vp[m] * a + bb;
        #pragma unroll
        for (int k = 0; k < 16; ++k) acc[k] += kp[k * NPIX + m] * vv;
    }
    #pragma unroll
    for (int k = 0; k < 16; ++k) {
        #pragma unroll
        for (int off = 32; off > 0; off >>= 1) acc[k] += __shfl_down(acc[k], off);
    }
    __shared__ float red[16][4];
    int wid = tid >> 6, lane = tid & 63;
    if (lane == 0) {
        #pragma unroll
        for (int k = 0; k < 16; ++k) red[k][wid] = acc[k];
    }
    __syncthreads();
    int vhh = v / 48, vtt = (v % 48) >> 4, vl = v & 15;
    size_t plane = ((size_t)(b * 2 + vhh) * 3 + vtt) * 512;
    if (tid < 16) {
        int k = tid;
        float val = red[k][0] + red[k][1] + red[k][2] + red[k][3];
        lc_g[plane + (k >> 3) * 128 + vl * 8 + (k & 7)] = f2bf(val);
    } else if (tid < 18) {
        int mq = 2 + (tid - 16);
        uint4 z; z.x = z.y = z.z = z.w = 0u;
        *(uint4*)&lc_g[plane + mq * 128 + vl * 8] = z;
    }
}

// ---------------- K5: fused MFMA position+content lambda --------------------
// grid (128 n-tiles of 8, 2 v-halves), 512 threads (8 waves).
// Phase 1 (per n): S[m32,(b,h)32] = P[n,m,k16] q[k,(b,h)]  (mfma 32x32x16)
// Phase 2 (per b=wave): Yt[v,(h',n)] += Vt[v,m] S[m,(h',n)] (mfma 16x16x32)
// Content lambda = extra zero-padded K iteration with S_ext=q, V_ext=lambda_c.
__global__ __launch_bounds__(512, 2) void k_main(const float* __restrict__ pos,
    const ushort16_t* __restrict__ qt_g, const ushort16_t* __restrict__ vt_g,
    const ushort16_t* __restrict__ lc_g, float* __restrict__ out)
{
    __shared__ __align__(16) ushort16_t q_s[4096];   // [n8][kh2][bh32][8]  8 KB
    __shared__ __align__(16) ushort16_t P_s[4096];   // [n8][kh2][m32][8]   8 KB
    __shared__ __align__(16) ushort16_t V_s[12288];  // [b8][vt3][mq4][v16][8] 24 KB
    __shared__ __align__(16) ushort16_t S_s[8192];   // [plane16][chunk64][8] 16 KB
    int tid  = threadIdx.x;
    int lane = tid & 63;
    int wave = tid >> 6;          // phase-1: n index; phase-2: b index
    int n0 = blockIdx.x * 8;
    int vh = blockIdx.y;

    // stage q: wave w stages 1 KB for n = n0+w
    dma16(qt_g + (size_t)(n0 + wave) * 512 + lane * 8, &q_s[wave * 512]);

    floatx4 acc[2][3];
    #pragma unroll
    for (int hg = 0; hg < 2; ++hg)
        #pragma unroll
        for (int vt = 0; vt < 3; ++vt)
            acc[hg][vt] = floatx4{0.f, 0.f, 0.f, 0.f};

    // phase-1 lane decode (column = b*4+h)
    int col1 = lane & 31, half = lane >> 5;
    int pb = col1 >> 2, ph = col1 & 3;
    int pplane = pb * 2 + (ph >> 1);
    int pf = pplane & 7;
    int pcb = ph & 1;
    // P staging decode
    int sm = tid & 31, snn = (tid >> 5) & 7, skh = (tid >> 8) & 1;
    int b2 = wave;

    for (int mt = 0; mt < 32; ++mt) {
        int m0 = mt * 32;
        __syncthreads();   // (A) previous phase-2 reads done
        // V DMA: wave stages its own b's 3 KB
        {
            const ushort16_t* src = vt_g
                + (size_t)(((b2 * 32 + mt) * 2 + vh) * 3) * 512;
            #pragma unroll
            for (int j = 0; j < 3; ++j)
                dma16(src + j * 512 + lane * 8, &V_s[b2 * 1536 + j * 512]);
        }
        // P stage: 8 fp32 -> 8 bf16 -> one b128 LDS write per thread
        {
            const float* p = pos + ((size_t)(n0 + snn) * 1024 + (m0 + sm)) * 16
                           + skh * 8;
            float4 f0 = *(const float4*)p;
            float4 f1 = *(const float4*)(p + 4);
            uint4 w;
            w.x = pk2(f0.x, f0.y); w.y = pk2(f0.z, f0.w);
            w.z = pk2(f1.x, f1.y); w.w = pk2(f1.z, f1.w);
            *(uint4*)&P_s[(snn * 2 + skh) * 256 + sm * 8] = w;
        }
        __syncthreads();   // (A2) staging + DMA visible
        // phase-1: n = wave
        {
            short8 afr = *(const short8*)&P_s[wave * 512 + half * 256 + col1 * 8];
            short8 bfr = *(const short8*)&q_s[wave * 512 + half * 256 + col1 * 8];
            floatx16 d;
            #pragma unroll
            for (int i = 0; i < 16; ++i) d[i] = 0.f;
            d = __builtin_amdgcn_mfma_f32_32x32x16_bf16(afr, bfr, d, 0, 0, 0);
            int nx = wave ^ pf;
            #pragma unroll
            for (int q = 0; q < 4; ++q) {
                int c = q * 16 + pcb * 8 + nx;
                uint2 wv;
                wv.x = pk2(d[q * 4 + 0], d[q * 4 + 1]);
                wv.y = pk2(d[q * 4 + 2], d[q * 4 + 3]);
                *(uint2*)&S_s[pplane * 512 + c * 8 + half * 4] = wv;
            }
        }
        __syncthreads();   // (B) S visible
        // phase-2: b = wave
        {
            short8 av[3];
            #pragma unroll
            for (int vt = 0; vt < 3; ++vt)
                av[vt] = *(const short8*)&V_s[b2 * 1536 + vt * 512 + lane * 8];
            #pragma unroll
            for (int hg = 0; hg < 2; ++hg) {
                int p2 = b2 * 2 + hg, f2 = p2 & 7;
                short8 bs = *(const short8*)&S_s[p2 * 512
                    + ((lane >> 4) * 16 + ((lane & 15) ^ f2)) * 8];
                #pragma unroll
                for (int vt = 0; vt < 3; ++vt)
                    acc[hg][vt] = __builtin_amdgcn_mfma_f32_16x16x32_bf16(
                        av[vt], bs, acc[hg][vt], 0, 0, 0);
            }
        }
    }

    // ---- content-lambda extension iteration ----
    __syncthreads();
    {
        const ushort16_t* src = lc_g + (size_t)((b2 * 2 + vh) * 3) * 512;
        #pragma unroll
        for (int j = 0; j < 3; ++j)
            dma16(src + j * 512 + lane * 8, &V_s[b2 * 1536 + j * 512]);
    }
    {
        // S_ext[(b,h) cols][k16] = q-hat; chunks mq0-1 from q_s, mq2-3 zero
        int bh = tid & 31, nn = (tid >> 5) & 7, kh = (tid >> 8) & 1;
        int b_ = bh >> 2, h_ = bh & 3;
        int pl = b_ * 2 + (h_ >> 1), f = pl & 7;
        short8 qv = *(const short8*)&q_s[nn * 512 + kh * 256 + bh * 8];
        int c = kh * 16 + (h_ & 1) * 8 + (nn ^ f);
        *(short8*)&S_s[pl * 512 + c * 8] = qv;
        int zp = tid >> 5, zr = tid & 31;
        int zc = (2 + (zr >> 4)) * 16 + ((zr & 15) ^ (zp & 7));
        uint4 z; z.x = z.y = z.z = z.w = 0u;
        *(uint4*)&S_s[zp * 512 + zc * 8] = z;
    }
    __syncthreads();
    {
        short8 av[3];
        #pragma unroll
        for (int vt = 0; vt < 3; ++vt)
            av[vt] = *(const short8*)&V_s[b2 * 1536 + vt * 512 + lane * 8];
        #pragma unroll
        for (int hg = 0; hg < 2; ++hg) {
            int p2 = b2 * 2 + hg, f2 = p2 & 7;
            short8 bs = *(const short8*)&S_s[p2 * 512
                + ((lane >> 4) * 16 + ((lane & 15) ^ f2)) * 8];
            #pragma unroll
            for (int vt = 0; vt < 3; ++vt)
                acc[hg][vt] = __builtin_amdgcn_mfma_f32_16x16x32_bf16(
                    av[vt], bs, acc[hg][vt], 0, 0, 0);
        }
    }

    // ---- epilogue: C/D col = (h',n) -> coalesced n stores ----
    {
        int cn = lane & 15;
        int nloc = cn & 7;
        #pragma unroll
        for (int hg = 0; hg < 2; ++hg) {
            int h = hg * 2 + (cn >> 3);
            #pragma unroll
            for (int vt = 0; vt < 3; ++vt) {
                #pragma unroll
                for (int r = 0; r < 4; ++r) {
                    int v = vh * 48 + vt * 16 + (lane >> 4) * 4 + r;
                    out[(size_t)(b2 * 384 + h * 96 + v) * 1024 + n0 + nloc]
                        = acc[hg][vt][r];
                }
            }
        }
    }
}

extern "C" void kernel_launch(void* const* d_in, const int* in_sizes, int n_in,
                              void* d_out, int out_size, void* d_ws, size_t ws_size,
                              hipStream_t stream) {
    const float* x   = (const float*)d_in[0];
    const float* Wq  = (const float*)d_in[1];
    const float* Wk  = (const float*)d_in[2];
    const float* Wv  = (const float*)d_in[3];
    const float* gq  = (const float*)d_in[4];
    const float* bq  = (const float*)d_in[5];
    const float* gv  = (const float*)d_in[6];
    const float* bv  = (const float*)d_in[7];
    const float* pos = (const float*)d_in[8];
    float* out = (float*)d_out;
    float* ws  = (float*)d_ws;

    float* qkv = ws;
    float* sA  = ws + 1441792;
    float* sB  = ws + 1441968;
    float* ksm = ws + 1442144;
    ushort16_t* qt_g = (ushort16_t*)(ws + 1573216);
    ushort16_t* vt_g = (ushort16_t*)(ws + 1835360);
    ushort16_t* lc_g = (ushort16_t*)(ws + 2228576);

    k_proj<<<dim3(4, 11, 8), dim3(256), 0, stream>>>(x, Wq, Wk, Wv, qkv);
    k_bnsm<<<dim3(288), dim3(256), 0, stream>>>(qkv, gq, bq, gv, bv, sA, sB, ksm);
    k_pack<<<dim3(208), dim3(512), 0, stream>>>(qkv, sA, sB, qt_g, vt_g);
    k_lambdac<<<dim3(96, 8), dim3(256), 0, stream>>>(ksm, qkv, sA, sB, lc_g);
    k_main<<<dim3(128, 2), dim3(512), 0, stream>>>(pos, qt_g, vt_g, lc_g, out);
}

// Round 3
// 203.906 us; speedup vs baseline: 1.9626x; 1.2773x over previous
//
#include <hip/hip_runtime.h>

typedef __attribute__((ext_vector_type(8))) short short8;
typedef __attribute__((ext_vector_type(16))) float floatx16;
typedef __attribute__((ext_vector_type(4))) float floatx4;
typedef unsigned short ushort16_t;
typedef unsigned int uint32;

#define BB 8
#define CC 384
#define NPIX 1024
#define TOTCH 176      // 64 q + 16 k + 96 v
#define BN_EPS 1e-5f

// ---------- helpers ----------
__device__ __forceinline__ ushort16_t f2bf(float x) {
    uint32 u = __float_as_uint(x);
    u += 0x7FFFu + ((u >> 16) & 1u);
    return (ushort16_t)(u >> 16);
}
__device__ __forceinline__ uint32 pk2(float a, float b) {
    uint32 ua = __float_as_uint(a); ua += 0x7FFFu + ((ua >> 16) & 1u);
    uint32 ub = __float_as_uint(b); ub += 0x7FFFu + ((ub >> 16) & 1u);
    return (ua >> 16) | (ub & 0xFFFF0000u);
}
__device__ __forceinline__ void dma16(const ushort16_t* g, ushort16_t* l) {
    __builtin_amdgcn_global_load_lds(
        (const __attribute__((address_space(1))) uint32*)g,
        (__attribute__((address_space(3))) uint32*)l, 16, 0, 0);
}

// ws layout (float units):
// qkv  [B][176][N]        @ 0         (1441792)
// sA   [176]              @ 1441792
// sB   [176]              @ 1441968
// ksm  [B][16][N]         @ 1442144   (131072)
// qt_g bf16 [n][kh2][bh32][8]                 @f 1573216 (262144 f)
// vt_g bf16 [b][mt32][vh2][vt3][mq4][v16][8]  @f 1835360 (393216 f)
// lc_g bf16 [b][vh2][vt3][mq4][v16][8]        @f 2228576 (12288 f)
// xbf  bf16 [col=b*1024+n][c384]              @f 2240864 (1572864 f)
// wbf  bf16 [row192][c384]                    @f 3813728 (36864 f)
// end 3850592 floats (~15.4 MB)

// ---------------- K0: transpose x -> xbf (bf16, k-contiguous); W -> wbf -----
__global__ __launch_bounds__(256) void k_xt(const float* __restrict__ x,
    const float* __restrict__ Wq, const float* __restrict__ Wk,
    const float* __restrict__ Wv,
    ushort16_t* __restrict__ xbf, ushort16_t* __restrict__ wbf)
{
    int bx = blockIdx.x, t = threadIdx.x;
    if (bx < 384) {
        int gi = bx * 256 + t;            // [0, 98304)
        int colg = gi & 2047;             // 4-col group
        int cg   = gi >> 11;              // c-group of 8
        int b  = colg >> 8;
        int n0 = (colg & 255) * 4;
        int c0 = cg * 8;
        int col0 = colg * 4;
        float vv[8][4];
        #pragma unroll
        for (int j = 0; j < 8; ++j) {
            float4 f = *(const float4*)(x + (size_t)b * (CC * NPIX)
                                          + (size_t)(c0 + j) * NPIX + n0);
            vv[j][0] = f.x; vv[j][1] = f.y; vv[j][2] = f.z; vv[j][3] = f.w;
        }
        #pragma unroll
        for (int cc = 0; cc < 4; ++cc) {
            uint4 w;
            w.x = pk2(vv[0][cc], vv[1][cc]);
            w.y = pk2(vv[2][cc], vv[3][cc]);
            w.z = pk2(vv[4][cc], vv[5][cc]);
            w.w = pk2(vv[6][cc], vv[7][cc]);
            *(uint4*)&xbf[(size_t)(col0 + cc) * CC + c0] = w;
        }
    } else {
        int idx8 = (bx - 384) * 256 + t;  // [0, 9216) = 192 rows * 48 groups
        int row = idx8 / 48;
        int j   = idx8 - row * 48;
        float4 f0, f1;
        if (row < 176) {
            const float* src;
            if (row < 64)       src = Wq + (size_t)row * CC;
            else if (row < 80)  src = Wk + (size_t)(row - 64) * CC;
            else                src = Wv + (size_t)(row - 80) * CC;
            f0 = *(const float4*)(src + j * 8);
            f1 = *(const float4*)(src + j * 8 + 4);
        } else {
            f0.x = f0.y = f0.z = f0.w = 0.f;
            f1 = f0;
        }
        uint4 w;
        w.x = pk2(f0.x, f0.y); w.y = pk2(f0.z, f0.w);
        w.z = pk2(f1.x, f1.y); w.w = pk2(f1.z, f1.w);
        *(uint4*)&wbf[(size_t)row * CC + j * 8] = w;
    }
}

// ---------------- K1: q/k/v projection via MFMA (no LDS) --------------------
// out[176, 8192] = W[176,384] x X[384,8192]; 16x16 tiles, K=32 per step.
__global__ __launch_bounds__(256) void k_proj(const ushort16_t* __restrict__ xbf,
    const ushort16_t* __restrict__ wbf, float* __restrict__ qkv)
{
    int t = threadIdx.x;
    int wave = t >> 6, lane = t & 63;
    int ct = blockIdx.x * 4 + wave;       // col tile [0,512)
    int r0 = blockIdx.y * 16;             // row base (176 = 11*16 exact)
    int col = ct * 16 + (lane & 15);
    int kh  = lane >> 4;                  // 0..3 (k-half of 8)
    const ushort16_t* ap = wbf + (size_t)(r0 + (lane & 15)) * CC + kh * 8;
    const ushort16_t* bp = xbf + (size_t)col * CC + kh * 8;
    floatx4 acc = {0.f, 0.f, 0.f, 0.f};
    short8 a0 = *(const short8*)ap;
    short8 b0 = *(const short8*)bp;
    #pragma unroll
    for (int k = 1; k < 12; ++k) {
        short8 a1 = *(const short8*)(ap + k * 32);
        short8 b1 = *(const short8*)(bp + k * 32);
        acc = __builtin_amdgcn_mfma_f32_16x16x32_bf16(a0, b0, acc, 0, 0, 0);
        a0 = a1; b0 = b1;
    }
    acc = __builtin_amdgcn_mfma_f32_16x16x32_bf16(a0, b0, acc, 0, 0, 0);
    int b = col >> 10, n = col & 1023;
    #pragma unroll
    for (int r = 0; r < 4; ++r) {
        int ch = r0 + (lane >> 4) * 4 + r;
        qkv[((size_t)b * TOTCH + ch) * NPIX + n] = acc[r];
    }
}

// ---------------- K2: BN stats + softmax (merged) ---------------------------
__global__ __launch_bounds__(256) void k_bnsm(const float* __restrict__ qkv,
    const float* __restrict__ gq, const float* __restrict__ bq,
    const float* __restrict__ gv, const float* __restrict__ bv,
    float* __restrict__ sA, float* __restrict__ sB, float* __restrict__ ksm)
{
    int bx = blockIdx.x, tid = threadIdx.x;
    int wid = tid >> 6, lane = tid & 63;
    if (bx < 160) {
        int ch = bx;
        int row; float gamma, beta;
        if (ch < 64) { row = ch; gamma = gq[ch]; beta = bq[ch]; }
        else { int j = ch - 64; row = 80 + j; gamma = gv[j]; beta = bv[j]; }
        float s = 0.f, ss = 0.f;
        for (int i = tid; i < BB * NPIX; i += 256) {
            int b = i >> 10, n = i & 1023;
            float val = qkv[((size_t)b * TOTCH + row) * NPIX + n];
            s += val; ss += val * val;
        }
        #pragma unroll
        for (int off = 32; off > 0; off >>= 1) {
            s  += __shfl_down(s, off);
            ss += __shfl_down(ss, off);
        }
        __shared__ float rs[4], rss[4];
        if (lane == 0) { rs[wid] = s; rss[wid] = ss; }
        __syncthreads();
        if (tid == 0) {
            float S  = rs[0] + rs[1] + rs[2] + rs[3];
            float SS = rss[0] + rss[1] + rss[2] + rss[3];
            float inv = 1.f / (BB * NPIX);
            float mean = S * inv;
            float var  = SS * inv - mean * mean;
            float a = gamma * rsqrtf(var + BN_EPS);
            sA[row] = a;
            sB[row] = beta - mean * a;
        }
    } else {
        int idx = bx - 160;
        int kc = idx & 15, b = idx >> 4;
        const float* rowp = qkv + ((size_t)b * TOTCH + 64 + kc) * NPIX;
        float v[4];
        #pragma unroll
        for (int j = 0; j < 4; ++j) v[j] = rowp[tid + 256 * j];
        float mx = fmaxf(fmaxf(v[0], v[1]), fmaxf(v[2], v[3]));
        #pragma unroll
        for (int off = 32; off > 0; off >>= 1) mx = fmaxf(mx, __shfl_down(mx, off));
        __shared__ float sm[4], ssum[4];
        if (lane == 0) sm[wid] = mx;
        __syncthreads();
        mx = fmaxf(fmaxf(sm[0], sm[1]), fmaxf(sm[2], sm[3]));
        float e[4], s = 0.f;
        #pragma unroll
        for (int j = 0; j < 4; ++j) { e[j] = __expf(v[j] - mx); s += e[j]; }
        #pragma unroll
        for (int off = 32; off > 0; off >>= 1) s += __shfl_down(s, off);
        if (lane == 0) ssum[wid] = s;
        __syncthreads();
        float inv = 1.f / (ssum[0] + ssum[1] + ssum[2] + ssum[3]);
        float* op = ksm + ((size_t)b * 16 + kc) * NPIX;
        #pragma unroll
        for (int j = 0; j < 4; ++j) op[tid + 256 * j] = e[j] * inv;
    }
}

// ---------------- K3: pack q-hat / v-hat into tiled bf16 buffers ------------
__global__ __launch_bounds__(256) void k_pack(const float* __restrict__ qkv,
    const float* __restrict__ sA, const float* __restrict__ sB,
    ushort16_t* __restrict__ qt_g, ushort16_t* __restrict__ vt_g)
{
    int bx = blockIdx.x, t = threadIdx.x;
    if (bx < 128) {
        // q part: qt_g[n][kh][bh][8]; one (n, bh) per thread
        int bh = t & 31, nn = (t >> 5) & 7;
        int n = bx * 8 + nn;
        int b = bh >> 2, h = bh & 3;
        float vals[16];
        #pragma unroll
        for (int k = 0; k < 16; ++k) {
            int ch = h * 16 + k;
            vals[k] = qkv[((size_t)b * TOTCH + ch) * NPIX + n] * sA[ch] + sB[ch];
        }
        uint4 w0, w1;
        w0.x = pk2(vals[0], vals[1]);  w0.y = pk2(vals[2], vals[3]);
        w0.z = pk2(vals[4], vals[5]);  w0.w = pk2(vals[6], vals[7]);
        w1.x = pk2(vals[8], vals[9]);  w1.y = pk2(vals[10], vals[11]);
        w1.z = pk2(vals[12], vals[13]); w1.w = pk2(vals[14], vals[15]);
        *(uint4*)&qt_g[(size_t)n * 512 + bh * 8]       = w0;
        *(uint4*)&qt_g[(size_t)n * 512 + 256 + bh * 8] = w1;
    } else {
        // v part: vt_g[b][mt][vh][vt][mq][vl][8]
        int gi = (bx - 128) * 256 + t;   // < 98304
        int m8 = gi & 127;
        int vg = (gi >> 7) % 96;
        int b  = gi / (96 * 128);
        int m  = m8 * 8;
        int row = 80 + vg;
        float a = sA[row], bb = sB[row];
        const float* p = qkv + ((size_t)b * TOTCH + row) * NPIX + m;
        float4 f0 = *(const float4*)p;
        float4 f1 = *(const float4*)(p + 4);
        uint4 w;
        w.x = pk2(f0.x * a + bb, f0.y * a + bb);
        w.y = pk2(f0.z * a + bb, f0.w * a + bb);
        w.z = pk2(f1.x * a + bb, f1.y * a + bb);
        w.w = pk2(f1.z * a + bb, f1.w * a + bb);
        int mt = m >> 5, mq = (m >> 3) & 3;
        int vhh = vg / 48, vtt = (vg % 48) >> 4, vl = vg & 15;
        size_t idx = ((((size_t)b * 32 + mt) * 2 + vhh) * 3 + vtt) * 512
                   + mq * 128 + vl * 8;
        *(uint4*)&vt_g[idx] = w;
    }
}

// ---------------- K4: content lambda -> tiled bf16 lc_g ---------------------
__global__ __launch_bounds__(256) void k_lambdac(const float* __restrict__ ksm,
    const float* __restrict__ qkv, const float* __restrict__ sA,
    const float* __restrict__ sB, ushort16_t* __restrict__ lc_g)
{
    int v = blockIdx.x, b = blockIdx.y, tid = threadIdx.x;
    int row = 80 + v;
    float a = sA[row], bb = sB[row];
    const float* vp = qkv + ((size_t)b * TOTCH + row) * NPIX;
    const float* kp = ksm + (size_t)b * 16 * NPIX;
    float acc[16];
    #pragma unroll
    for (int k = 0; k < 16; ++k) acc[k] = 0.f;
    for (int m = tid; m < NPIX; m += 256) {
        float vv = vp[m] * a + bb;
        #pragma unroll
        for (int k = 0; k < 16; ++k) acc[k] += kp[k * NPIX + m] * vv;
    }
    #pragma unroll
    for (int k = 0; k < 16; ++k) {
        #pragma unroll
        for (int off = 32; off > 0; off >>= 1) acc[k] += __shfl_down(acc[k], off);
    }
    __shared__ float red[16][4];
    int wid = tid >> 6, lane = tid & 63;
    if (lane == 0) {
        #pragma unroll
        for (int k = 0; k < 16; ++k) red[k][wid] = acc[k];
    }
    __syncthreads();
    int vhh = v / 48, vtt = (v % 48) >> 4, vl = v & 15;
    size_t plane = ((size_t)(b * 2 + vhh) * 3 + vtt) * 512;
    if (tid < 16) {
        int k = tid;
        float val = red[k][0] + red[k][1] + red[k][2] + red[k][3];
        lc_g[plane + (k >> 3) * 128 + vl * 8 + (k & 7)] = f2bf(val);
    } else if (tid < 18) {
        int mq = 2 + (tid - 16);
        uint4 z; z.x = z.y = z.z = z.w = 0u;
        *(uint4*)&lc_g[plane + mq * 128 + vl * 8] = z;
    }
}

// ---------------- K5: fused MFMA position+content lambda --------------------
__global__ __launch_bounds__(512, 2) void k_main(const float* __restrict__ pos,
    const ushort16_t* __restrict__ qt_g, const ushort16_t* __restrict__ vt_g,
    const ushort16_t* __restrict__ lc_g, float* __restrict__ out)
{
    __shared__ __align__(16) ushort16_t q_s[4096];   // [n8][kh2][bh32][8]  8 KB
    __shared__ __align__(16) ushort16_t P_s[4096];   // [n8][kh2][m32][8]   8 KB
    __shared__ __align__(16) ushort16_t V_s[12288];  // [b8][vt3][mq4][v16][8] 24 KB
    __shared__ __align__(16) ushort16_t S_s[8192];   // [plane16][chunk64][8] 16 KB
    int tid  = threadIdx.x;
    int lane = tid & 63;
    int wave = tid >> 6;          // phase-1: n index; phase-2: b index
    int n0 = blockIdx.x * 8;
    int vh = blockIdx.y;

    dma16(qt_g + (size_t)(n0 + wave) * 512 + lane * 8, &q_s[wave * 512]);

    floatx4 acc[2][3];
    #pragma unroll
    for (int hg = 0; hg < 2; ++hg)
        #pragma unroll
        for (int vt = 0; vt < 3; ++vt)
            acc[hg][vt] = floatx4{0.f, 0.f, 0.f, 0.f};

    int col1 = lane & 31, half = lane >> 5;
    int pb = col1 >> 2, ph = col1 & 3;
    int pplane = pb * 2 + (ph >> 1);
    int pf = pplane & 7;
    int pcb = ph & 1;
    int sm = tid & 31, snn = (tid >> 5) & 7, skh = (tid >> 8) & 1;
    int b2 = wave;

    for (int mt = 0; mt < 32; ++mt) {
        int m0 = mt * 32;
        __syncthreads();   // (A) previous phase-2 reads done
        {
            const ushort16_t* src = vt_g
                + (size_t)(((b2 * 32 + mt) * 2 + vh) * 3) * 512;
            #pragma unroll
            for (int j = 0; j < 3; ++j)
                dma16(src + j * 512 + lane * 8, &V_s[b2 * 1536 + j * 512]);
        }
        {
            const float* p = pos + ((size_t)(n0 + snn) * 1024 + (m0 + sm)) * 16
                           + skh * 8;
            float4 f0 = *(const float4*)p;
            float4 f1 = *(const float4*)(p + 4);
            uint4 w;
            w.x = pk2(f0.x, f0.y); w.y = pk2(f0.z, f0.w);
            w.z = pk2(f1.x, f1.y); w.w = pk2(f1.z, f1.w);
            *(uint4*)&P_s[(snn * 2 + skh) * 256 + sm * 8] = w;
        }
        __syncthreads();   // (A2) staging + DMA visible
        {
            short8 afr = *(const short8*)&P_s[wave * 512 + half * 256 + col1 * 8];
            short8 bfr = *(const short8*)&q_s[wave * 512 + half * 256 + col1 * 8];
            floatx16 d;
            #pragma unroll
            for (int i = 0; i < 16; ++i) d[i] = 0.f;
            d = __builtin_amdgcn_mfma_f32_32x32x16_bf16(afr, bfr, d, 0, 0, 0);
            int nx = wave ^ pf;
            #pragma unroll
            for (int q = 0; q < 4; ++q) {
                int c = q * 16 + pcb * 8 + nx;
                uint2 wv;
                wv.x = pk2(d[q * 4 + 0], d[q * 4 + 1]);
                wv.y = pk2(d[q * 4 + 2], d[q * 4 + 3]);
                *(uint2*)&S_s[pplane * 512 + c * 8 + half * 4] = wv;
            }
        }
        __syncthreads();   // (B) S visible
        {
            short8 av[3];
            #pragma unroll
            for (int vt = 0; vt < 3; ++vt)
                av[vt] = *(const short8*)&V_s[b2 * 1536 + vt * 512 + lane * 8];
            #pragma unroll
            for (int hg = 0; hg < 2; ++hg) {
                int p2 = b2 * 2 + hg, f2 = p2 & 7;
                short8 bs = *(const short8*)&S_s[p2 * 512
                    + ((lane >> 4) * 16 + ((lane & 15) ^ f2)) * 8];
                #pragma unroll
                for (int vt = 0; vt < 3; ++vt)
                    acc[hg][vt] = __builtin_amdgcn_mfma_f32_16x16x32_bf16(
                        av[vt], bs, acc[hg][vt], 0, 0, 0);
            }
        }
    }

    // ---- content-lambda extension iteration ----
    __syncthreads();
    {
        const ushort16_t* src = lc_g + (size_t)((b2 * 2 + vh) * 3) * 512;
        #pragma unroll
        for (int j = 0; j < 3; ++j)
            dma16(src + j * 512 + lane * 8, &V_s[b2 * 1536 + j * 512]);
    }
    {
        int bh = tid & 31, nn = (tid >> 5) & 7, kh = (tid >> 8) & 1;
        int b_ = bh >> 2, h_ = bh & 3;
        int pl = b_ * 2 + (h_ >> 1), f = pl & 7;
        short8 qv = *(const short8*)&q_s[nn * 512 + kh * 256 + bh * 8];
        int c = kh * 16 + (h_ & 1) * 8 + (nn ^ f);
        *(short8*)&S_s[pl * 512 + c * 8] = qv;
        int zp = tid >> 5, zr = tid & 31;
        int zc = (2 + (zr >> 4)) * 16 + ((zr & 15) ^ (zp & 7));
        uint4 z; z.x = z.y = z.z = z.w = 0u;
        *(uint4*)&S_s[zp * 512 + zc * 8] = z;
    }
    __syncthreads();
    {
        short8 av[3];
        #pragma unroll
        for (int vt = 0; vt < 3; ++vt)
            av[vt] = *(const short8*)&V_s[b2 * 1536 + vt * 512 + lane * 8];
        #pragma unroll
        for (int hg = 0; hg < 2; ++hg) {
            int p2 = b2 * 2 + hg, f2 = p2 & 7;
            short8 bs = *(const short8*)&S_s[p2 * 512
                + ((lane >> 4) * 16 + ((lane & 15) ^ f2)) * 8];
            #pragma unroll
            for (int vt = 0; vt < 3; ++vt)
                acc[hg][vt] = __builtin_amdgcn_mfma_f32_16x16x32_bf16(
                    av[vt], bs, acc[hg][vt], 0, 0, 0);
        }
    }

    // ---- epilogue ----
    {
        int cn = lane & 15;
        int nloc = cn & 7;
        #pragma unroll
        for (int hg = 0; hg < 2; ++hg) {
            int h = hg * 2 + (cn >> 3);
            #pragma unroll
            for (int vt = 0; vt < 3; ++vt) {
                #pragma unroll
                for (int r = 0; r < 4; ++r) {
                    int v = vh * 48 + vt * 16 + (lane >> 4) * 4 + r;
                    out[(size_t)(b2 * 384 + h * 96 + v) * 1024 + n0 + nloc]
                        = acc[hg][vt][r];
                }
            }
        }
    }
}

extern "C" void kernel_launch(void* const* d_in, const int* in_sizes, int n_in,
                              void* d_out, int out_size, void* d_ws, size_t ws_size,
                              hipStream_t stream) {
    const float* x   = (const float*)d_in[0];
    const float* Wq  = (const float*)d_in[1];
    const float* Wk  = (const float*)d_in[2];
    const float* Wv  = (const float*)d_in[3];
    const float* gq  = (const float*)d_in[4];
    const float* bq  = (const float*)d_in[5];
    const float* gv  = (const float*)d_in[6];
    const float* bv  = (const float*)d_in[7];
    const float* pos = (const float*)d_in[8];
    float* out = (float*)d_out;
    float* ws  = (float*)d_ws;

    float* qkv = ws;
    float* sA  = ws + 1441792;
    float* sB  = ws + 1441968;
    float* ksm = ws + 1442144;
    ushort16_t* qt_g = (ushort16_t*)(ws + 1573216);
    ushort16_t* vt_g = (ushort16_t*)(ws + 1835360);
    ushort16_t* lc_g = (ushort16_t*)(ws + 2228576);
    ushort16_t* xbf  = (ushort16_t*)(ws + 2240864);
    ushort16_t* wbf  = (ushort16_t*)(ws + 3813728);

    k_xt<<<dim3(420), dim3(256), 0, stream>>>(x, Wq, Wk, Wv, xbf, wbf);
    k_proj<<<dim3(128, 11), dim3(256), 0, stream>>>(xbf, wbf, qkv);
    k_bnsm<<<dim3(288), dim3(256), 0, stream>>>(qkv, gq, bq, gv, bv, sA, sB, ksm);
    k_pack<<<dim3(512), dim3(256), 0, stream>>>(qkv, sA, sB, qt_g, vt_g);
    k_lambdac<<<dim3(96, 8), dim3(256), 0, stream>>>(ksm, qkv, sA, sB, lc_g);
    k_main<<<dim3(128, 2), dim3(512), 0, stream>>>(pos, qt_g, vt_g, lc_g, out);
}

// Round 4
// 184.762 us; speedup vs baseline: 2.1659x; 1.1036x over previous
//
#include <hip/hip_runtime.h>

typedef __attribute__((ext_vector_type(8))) short short8;
typedef __attribute__((ext_vector_type(16))) float floatx16;
typedef __attribute__((ext_vector_type(4))) float floatx4;
typedef unsigned short ushort16_t;
typedef unsigned int uint32;

#define BB 8
#define CC 384
#define NPIX 1024
#define TOTCH 176      // 64 q + 16 k + 96 v
#define BN_EPS 1e-5f

// ---------- helpers ----------
__device__ __forceinline__ ushort16_t f2bf(float x) {
    uint32 u = __float_as_uint(x);
    u += 0x7FFFu + ((u >> 16) & 1u);
    return (ushort16_t)(u >> 16);
}
__device__ __forceinline__ uint32 pk2(float a, float b) {
    uint32 ua = __float_as_uint(a); ua += 0x7FFFu + ((ua >> 16) & 1u);
    uint32 ub = __float_as_uint(b); ub += 0x7FFFu + ((ub >> 16) & 1u);
    return (ua >> 16) | (ub & 0xFFFF0000u);
}
__device__ __forceinline__ void dma16(const ushort16_t* g, ushort16_t* l) {
    __builtin_amdgcn_global_load_lds(
        (const __attribute__((address_space(1))) uint32*)g,
        (__attribute__((address_space(3))) uint32*)l, 16, 0, 0);
}
__device__ __forceinline__ int div48(int x) {   // valid for x < 16384
    return (int)(((unsigned)x * 21846u) >> 20);
}

// ws layout (float units):
// qkv  [B][176][N]        @ 0         (1441792)
// sA   [176]              @ 1441792
// sB   [176]              @ 1441968
// ksm  [B][16][N]         @ 1442144   (131072)
// qt_g bf16 [n][kh2][bh32][8]                 @f 1573216 (262144 f)
// vt_g bf16 [b][mt32][vh2][vt3][mq4][v16][8]  @f 1835360 (393216 f)
// lc_g bf16 [b][vh2][vt3][mq4][v16][8]        @f 2228576 (12288 f)
// xbf  bf16 [col=b*1024+n][c384]              @f 2240864 (1572864 f)
// wbf  bf16 [row192][c384]                    @f 3813728 (36864 f)

// ---------------- K0: transpose x -> xbf via LDS; W -> wbf ------------------
__global__ __launch_bounds__(256) void k_xt(const float* __restrict__ x,
    const float* __restrict__ Wq, const float* __restrict__ Wk,
    const float* __restrict__ Wv,
    ushort16_t* __restrict__ xbf, ushort16_t* __restrict__ wbf)
{
    int bx = blockIdx.x, t = threadIdx.x;
    if (bx < 256) {
        // 32 cols x 384 c per block, bounced through LDS T[n][c]
        __shared__ __align__(16) ushort16_t T[32 * 392];  // pad c-stride to 392
        int col0 = bx * 32;
        int b = col0 >> 10, nbase = col0 & 1023;
        const float* xb = x + (size_t)b * (CC * NPIX) + nbase;
        #pragma unroll
        for (int j = 0; j < 12; ++j) {
            int idx = t + 256 * j;        // [0, 3072)
            int c = idx >> 3, ng = idx & 7;
            float4 f = *(const float4*)(xb + (size_t)c * NPIX + ng * 4);
            int n = ng * 4;
            T[(n + 0) * 392 + c] = f2bf(f.x);
            T[(n + 1) * 392 + c] = f2bf(f.y);
            T[(n + 2) * 392 + c] = f2bf(f.z);
            T[(n + 3) * 392 + c] = f2bf(f.w);
        }
        __syncthreads();
        #pragma unroll
        for (int j = 0; j < 6; ++j) {
            int task = t + 256 * j;       // [0, 1536) = 32 cols x 48 chunks
            int col = div48(task);
            int ch  = task - col * 48;
            uint4 w = *(const uint4*)&T[col * 392 + ch * 8];
            *(uint4*)&xbf[(size_t)(col0 + col) * CC + ch * 8] = w;
        }
    } else {
        // W conversion: 192 rows x 48 chunks of 8 = 9216 tasks over 4 blocks
        #pragma unroll
        for (int jj = 0; jj < 9; ++jj) {
            int idx8 = ((bx - 256) * 9 + jj) * 256 + t;   // [0, 9216)
            int row = div48(idx8);
            int g   = idx8 - row * 48;
            float4 f0, f1;
            if (row < 176) {
                const float* src;
                if (row < 64)       src = Wq + (size_t)row * CC;
                else if (row < 80)  src = Wk + (size_t)(row - 64) * CC;
                else                src = Wv + (size_t)(row - 80) * CC;
                f0 = *(const float4*)(src + g * 8);
                f1 = *(const float4*)(src + g * 8 + 4);
            } else {
                f0.x = f0.y = f0.z = f0.w = 0.f;
                f1 = f0;
            }
            uint4 w;
            w.x = pk2(f0.x, f0.y); w.y = pk2(f0.z, f0.w);
            w.z = pk2(f1.x, f1.y); w.w = pk2(f1.z, f1.w);
            *(uint4*)&wbf[(size_t)row * CC + g * 8] = w;
        }
    }
}

// ---------------- K1: q/k/v projection via MFMA (no LDS) --------------------
__global__ __launch_bounds__(256) void k_proj(const ushort16_t* __restrict__ xbf,
    const ushort16_t* __restrict__ wbf, float* __restrict__ qkv)
{
    int t = threadIdx.x;
    int wave = t >> 6, lane = t & 63;
    int ct = blockIdx.x * 4 + wave;       // col tile [0,512)
    int r0 = blockIdx.y * 16;             // row base (176 = 11*16 exact)
    int col = ct * 16 + (lane & 15);
    int kh  = lane >> 4;                  // 0..3 (k-half of 8)
    const ushort16_t* ap = wbf + (size_t)(r0 + (lane & 15)) * CC + kh * 8;
    const ushort16_t* bp = xbf + (size_t)col * CC + kh * 8;
    floatx4 acc = {0.f, 0.f, 0.f, 0.f};
    short8 a0 = *(const short8*)ap;
    short8 b0 = *(const short8*)bp;
    #pragma unroll
    for (int k = 1; k < 12; ++k) {
        short8 a1 = *(const short8*)(ap + k * 32);
        short8 b1 = *(const short8*)(bp + k * 32);
        acc = __builtin_amdgcn_mfma_f32_16x16x32_bf16(a0, b0, acc, 0, 0, 0);
        a0 = a1; b0 = b1;
    }
    acc = __builtin_amdgcn_mfma_f32_16x16x32_bf16(a0, b0, acc, 0, 0, 0);
    int b = col >> 10, n = col & 1023;
    #pragma unroll
    for (int r = 0; r < 4; ++r) {
        int ch = r0 + (lane >> 4) * 4 + r;
        qkv[((size_t)b * TOTCH + ch) * NPIX + n] = acc[r];
    }
}

// ---------------- K2: BN stats + softmax (merged, float4) -------------------
__global__ __launch_bounds__(256) void k_bnsm(const float* __restrict__ qkv,
    const float* __restrict__ gq, const float* __restrict__ bq,
    const float* __restrict__ gv, const float* __restrict__ bv,
    float* __restrict__ sA, float* __restrict__ sB, float* __restrict__ ksm)
{
    int bx = blockIdx.x, tid = threadIdx.x;
    int wid = tid >> 6, lane = tid & 63;
    if (bx < 160) {
        int ch = bx;
        int row; float gamma, beta;
        if (ch < 64) { row = ch; gamma = gq[ch]; beta = bq[ch]; }
        else { int j = ch - 64; row = 80 + j; gamma = gv[j]; beta = bv[j]; }
        float s = 0.f, ss = 0.f;
        #pragma unroll
        for (int j = 0; j < 8; ++j) {
            int i4 = tid + 256 * j;       // [0, 2048) float4s
            int b = i4 >> 8, n4 = i4 & 255;
            float4 f = *(const float4*)(qkv + ((size_t)b * TOTCH + row) * NPIX
                                            + n4 * 4);
            s  += f.x + f.y + f.z + f.w;
            ss += f.x * f.x + f.y * f.y + f.z * f.z + f.w * f.w;
        }
        #pragma unroll
        for (int off = 32; off > 0; off >>= 1) {
            s  += __shfl_down(s, off);
            ss += __shfl_down(ss, off);
        }
        __shared__ float rs[4], rss[4];
        if (lane == 0) { rs[wid] = s; rss[wid] = ss; }
        __syncthreads();
        if (tid == 0) {
            float S  = rs[0] + rs[1] + rs[2] + rs[3];
            float SS = rss[0] + rss[1] + rss[2] + rss[3];
            float inv = 1.f / (BB * NPIX);
            float mean = S * inv;
            float var  = SS * inv - mean * mean;
            float a = gamma * rsqrtf(var + BN_EPS);
            sA[row] = a;
            sB[row] = beta - mean * a;
        }
    } else {
        int idx = bx - 160;
        int kc = idx & 15, b = idx >> 4;
        const float* rowp = qkv + ((size_t)b * TOTCH + 64 + kc) * NPIX;
        float4 v4 = *(const float4*)(rowp + tid * 4);
        float v[4] = {v4.x, v4.y, v4.z, v4.w};
        float mx = fmaxf(fmaxf(v[0], v[1]), fmaxf(v[2], v[3]));
        #pragma unroll
        for (int off = 32; off > 0; off >>= 1) mx = fmaxf(mx, __shfl_down(mx, off));
        __shared__ float sm[4], ssum[4];
        if (lane == 0) sm[wid] = mx;
        __syncthreads();
        mx = fmaxf(fmaxf(sm[0], sm[1]), fmaxf(sm[2], sm[3]));
        float e[4], s = 0.f;
        #pragma unroll
        for (int j = 0; j < 4; ++j) { e[j] = __expf(v[j] - mx); s += e[j]; }
        #pragma unroll
        for (int off = 32; off > 0; off >>= 1) s += __shfl_down(s, off);
        if (lane == 0) ssum[wid] = s;
        __syncthreads();
        float inv = 1.f / (ssum[0] + ssum[1] + ssum[2] + ssum[3]);
        float4 o;
        o.x = e[0] * inv; o.y = e[1] * inv; o.z = e[2] * inv; o.w = e[3] * inv;
        *(float4*)(ksm + ((size_t)b * 16 + kc) * NPIX + tid * 4) = o;
    }
}

// ---------------- K3: pack q/v (bf16 tiled) + content lambda (fused) --------
__global__ __launch_bounds__(256) void k_packlc(const float* __restrict__ qkv,
    const float* __restrict__ sA, const float* __restrict__ sB,
    const float* __restrict__ ksm,
    ushort16_t* __restrict__ qt_g, ushort16_t* __restrict__ vt_g,
    ushort16_t* __restrict__ lc_g)
{
    int bx = blockIdx.x, t = threadIdx.x;
    if (bx < 128) {
        // q part: qt_g[n][kh][bh][8]; one (n, bh) per thread
        int bh = t & 31, nn = (t >> 5) & 7;
        int n = bx * 8 + nn;
        int b = bh >> 2, h = bh & 3;
        float vals[16];
        #pragma unroll
        for (int k = 0; k < 16; ++k) {
            int ch = h * 16 + k;
            vals[k] = qkv[((size_t)b * TOTCH + ch) * NPIX + n] * sA[ch] + sB[ch];
        }
        uint4 w0, w1;
        w0.x = pk2(vals[0], vals[1]);  w0.y = pk2(vals[2], vals[3]);
        w0.z = pk2(vals[4], vals[5]);  w0.w = pk2(vals[6], vals[7]);
        w1.x = pk2(vals[8], vals[9]);  w1.y = pk2(vals[10], vals[11]);
        w1.z = pk2(vals[12], vals[13]); w1.w = pk2(vals[14], vals[15]);
        *(uint4*)&qt_g[(size_t)n * 512 + bh * 8]       = w0;
        *(uint4*)&qt_g[(size_t)n * 512 + 256 + bh * 8] = w1;
    } else if (bx < 512) {
        // v part: vt_g[b][mt][vh][vt][mq][vl][8]
        int gi = (bx - 128) * 256 + t;   // < 98304
        int m8 = gi & 127;
        int vg = (gi >> 7) % 96;
        int b  = gi / (96 * 128);
        int m  = m8 * 8;
        int row = 80 + vg;
        float a = sA[row], bb = sB[row];
        const float* p = qkv + ((size_t)b * TOTCH + row) * NPIX + m;
        float4 f0 = *(const float4*)p;
        float4 f1 = *(const float4*)(p + 4);
        uint4 w;
        w.x = pk2(f0.x * a + bb, f0.y * a + bb);
        w.y = pk2(f0.z * a + bb, f0.w * a + bb);
        w.z = pk2(f1.x * a + bb, f1.y * a + bb);
        w.w = pk2(f1.z * a + bb, f1.w * a + bb);
        int mt = m >> 5, mq = (m >> 3) & 3;
        int vhh = vg / 48, vtt = (vg % 48) >> 4, vl = vg & 15;
        size_t idx = ((((size_t)b * 32 + mt) * 2 + vhh) * 3 + vtt) * 512
                   + mq * 128 + vl * 8;
        *(uint4*)&vt_g[idx] = w;
    } else {
        // content lambda
        int gi = bx - 512;
        int v = gi % 96, b = gi / 96;
        int row = 80 + v;
        float a = sA[row], bb = sB[row];
        const float* vp = qkv + ((size_t)b * TOTCH + row) * NPIX;
        const float* kp = ksm + (size_t)b * 16 * NPIX;
        float acc[16];
        #pragma unroll
        for (int k = 0; k < 16; ++k) acc[k] = 0.f;
        for (int m = t; m < NPIX; m += 256) {
            float vv = vp[m] * a + bb;
            #pragma unroll
            for (int k = 0; k < 16; ++k) acc[k] += kp[k * NPIX + m] * vv;
        }
        #pragma unroll
        for (int k = 0; k < 16; ++k) {
            #pragma unroll
            for (int off = 32; off > 0; off >>= 1)
                acc[k] += __shfl_down(acc[k], off);
        }
        __shared__ float red[16][4];
        int wid = t >> 6, lane = t & 63;
        if (lane == 0) {
            #pragma unroll
            for (int k = 0; k < 16; ++k) red[k][wid] = acc[k];
        }
        __syncthreads();
        int vhh = v / 48, vtt = (v % 48) >> 4, vl = v & 15;
        size_t plane = ((size_t)(b * 2 + vhh) * 3 + vtt) * 512;
        if (t < 16) {
            int k = t;
            float val = red[k][0] + red[k][1] + red[k][2] + red[k][3];
            lc_g[plane + (k >> 3) * 128 + vl * 8 + (k & 7)] = f2bf(val);
        } else if (t < 18) {
            int mq = 2 + (t - 16);
            uint4 z; z.x = z.y = z.z = z.w = 0u;
            *(uint4*)&lc_g[plane + mq * 128 + vl * 8] = z;
        }
    }
}

// ---------------- K4: fused MFMA position+content lambda (pipelined) --------
// grid (128 n-tiles of 8, 2 v-halves), 512 threads (8 waves).
// 2 barriers/iter; P prefetched to regs 1 iter ahead; V dma'd 1 iter ahead.
__global__ __launch_bounds__(512, 2) void k_main(const float* __restrict__ pos,
    const ushort16_t* __restrict__ qt_g, const ushort16_t* __restrict__ vt_g,
    const ushort16_t* __restrict__ lc_g, float* __restrict__ out)
{
    __shared__ __align__(16) ushort16_t P_s[8192];   // 2 x [n8][kh2][m32][8] 16 KB
    __shared__ __align__(16) ushort16_t V_s[24576];  // 2 x [b8][vt3][mq4][v16][8] 48 KB
    __shared__ __align__(16) ushort16_t S_s[8192];   // [plane16][chunk64][8] 16 KB
    int tid  = threadIdx.x;
    int lane = tid & 63;
    int wave = tid >> 6;          // phase-1: n index; phase-2: b index
    int n0 = blockIdx.x * 8;
    int vh = blockIdx.y;

    int col1 = lane & 31, half = lane >> 5;
    int pb = col1 >> 2, ph = col1 & 3;
    int pplane = pb * 2 + (ph >> 1);
    int pf = pplane & 7;
    int pcb = ph & 1;
    int sm = tid & 31, snn = (tid >> 5) & 7, skh = (tid >> 8) & 1;
    int b2 = wave;

    // q fragment: one short8 per lane, fixed for whole kernel
    short8 qfr = *(const short8*)(qt_g + (size_t)(n0 + wave) * 512
                                  + half * 256 + col1 * 8);

    floatx4 acc[2][3];
    #pragma unroll
    for (int hg = 0; hg < 2; ++hg)
        #pragma unroll
        for (int vt = 0; vt < 3; ++vt)
            acc[hg][vt] = floatx4{0.f, 0.f, 0.f, 0.f};

    const float* pbase = pos + ((size_t)(n0 + snn) * 1024 + sm) * 16 + skh * 8;

    // ---- prologue: stage P(0), dma V(0) ----
    {
        float4 f0 = *(const float4*)pbase;
        float4 f1 = *(const float4*)(pbase + 4);
        uint4 w;
        w.x = pk2(f0.x, f0.y); w.y = pk2(f0.z, f0.w);
        w.z = pk2(f1.x, f1.y); w.w = pk2(f1.z, f1.w);
        *(uint4*)&P_s[(snn * 2 + skh) * 256 + sm * 8] = w;
        const ushort16_t* src = vt_g + (size_t)(((b2 * 32) * 2 + vh) * 3) * 512;
        #pragma unroll
        for (int j = 0; j < 3; ++j)
            dma16(src + j * 512 + lane * 8, &V_s[b2 * 1536 + j * 512]);
    }
    __syncthreads();

    for (int it = 0; it < 32; ++it) {
        // a: prefetch P(it+1) into registers
        float4 pf0, pf1;
        if (it < 31) {
            const float* p = pbase + (size_t)(it + 1) * 32 * 16;
            pf0 = *(const float4*)p;
            pf1 = *(const float4*)(p + 4);
        }
        // b: phase-1 (n = wave): S = P * q
        {
            short8 afr = *(const short8*)&P_s[(it & 1) * 4096
                + wave * 512 + half * 256 + col1 * 8];
            floatx16 d;
            #pragma unroll
            for (int i = 0; i < 16; ++i) d[i] = 0.f;
            d = __builtin_amdgcn_mfma_f32_32x32x16_bf16(afr, qfr, d, 0, 0, 0);
            int nx = wave ^ pf;
            #pragma unroll
            for (int q = 0; q < 4; ++q) {
                int c = q * 16 + pcb * 8 + nx;
                uint2 wv;
                wv.x = pk2(d[q * 4 + 0], d[q * 4 + 1]);
                wv.y = pk2(d[q * 4 + 2], d[q * 4 + 3]);
                *(uint2*)&S_s[pplane * 512 + c * 8 + half * 4] = wv;
            }
        }
        __syncthreads();   // S visible; F2(it-1) fully done; P_s[(it+1)&1] free
        // e: dma V(it+1) into other buffer
        if (it < 31) {
            const ushort16_t* src = vt_g
                + (size_t)(((b2 * 32 + it + 1) * 2 + vh) * 3) * 512;
            #pragma unroll
            for (int j = 0; j < 3; ++j)
                dma16(src + j * 512 + lane * 8,
                      &V_s[((it + 1) & 1) * 12288 + b2 * 1536 + j * 512]);
        }
        // f: phase-2 (b = wave): acc += V * S
        {
            int vb = (it & 1) * 12288;
            short8 av[3];
            #pragma unroll
            for (int vt = 0; vt < 3; ++vt)
                av[vt] = *(const short8*)&V_s[vb + b2 * 1536 + vt * 512 + lane * 8];
            #pragma unroll
            for (int hg = 0; hg < 2; ++hg) {
                int p2 = b2 * 2 + hg, f2 = p2 & 7;
                short8 bs = *(const short8*)&S_s[p2 * 512
                    + ((lane >> 4) * 16 + ((lane & 15) ^ f2)) * 8];
                #pragma unroll
                for (int vt = 0; vt < 3; ++vt)
                    acc[hg][vt] = __builtin_amdgcn_mfma_f32_16x16x32_bf16(
                        av[vt], bs, acc[hg][vt], 0, 0, 0);
            }
        }
        // d: write prefetched P regs into other P buffer
        if (it < 31) {
            uint4 w;
            w.x = pk2(pf0.x, pf0.y); w.y = pk2(pf0.z, pf0.w);
            w.z = pk2(pf1.x, pf1.y); w.w = pk2(pf1.z, pf1.w);
            *(uint4*)&P_s[((it + 1) & 1) * 4096 + (snn * 2 + skh) * 256 + sm * 8] = w;
        }
        __syncthreads();   // P_s, V dma visible for next iter
    }

    // ---- content-lambda extension iteration ----
    {
        const ushort16_t* src = lc_g + (size_t)((b2 * 2 + vh) * 3) * 512;
        #pragma unroll
        for (int j = 0; j < 3; ++j)
            dma16(src + j * 512 + lane * 8, &V_s[b2 * 1536 + j * 512]);
    }
    {
        // S_ext from register q fragment (same lane decode as phase-1)
        int c = half * 16 + pcb * 8 + (wave ^ pf);
        *(short8*)&S_s[pplane * 512 + c * 8] = qfr;
        int zp = tid >> 5, zr = tid & 31;
        int zc = (2 + (zr >> 4)) * 16 + ((zr & 15) ^ (zp & 7));
        uint4 z; z.x = z.y = z.z = z.w = 0u;
        *(uint4*)&S_s[zp * 512 + zc * 8] = z;
    }
    __syncthreads();
    {
        short8 av[3];
        #pragma unroll
        for (int vt = 0; vt < 3; ++vt)
            av[vt] = *(const short8*)&V_s[b2 * 1536 + vt * 512 + lane * 8];
        #pragma unroll
        for (int hg = 0; hg < 2; ++hg) {
            int p2 = b2 * 2 + hg, f2 = p2 & 7;
            short8 bs = *(const short8*)&S_s[p2 * 512
                + ((lane >> 4) * 16 + ((lane & 15) ^ f2)) * 8];
            #pragma unroll
            for (int vt = 0; vt < 3; ++vt)
                acc[hg][vt] = __builtin_amdgcn_mfma_f32_16x16x32_bf16(
                    av[vt], bs, acc[hg][vt], 0, 0, 0);
        }
    }

    // ---- epilogue ----
    {
        int cn = lane & 15;
        int nloc = cn & 7;
        #pragma unroll
        for (int hg = 0; hg < 2; ++hg) {
            int h = hg * 2 + (cn >> 3);
            #pragma unroll
            for (int vt = 0; vt < 3; ++vt) {
                #pragma unroll
                for (int r = 0; r < 4; ++r) {
                    int v = vh * 48 + vt * 16 + (lane >> 4) * 4 + r;
                    out[(size_t)(b2 * 384 + h * 96 + v) * 1024 + n0 + nloc]
                        = acc[hg][vt][r];
                }
            }
        }
    }
}

extern "C" void kernel_launch(void* const* d_in, const int* in_sizes, int n_in,
                              void* d_out, int out_size, void* d_ws, size_t ws_size,
                              hipStream_t stream) {
    const float* x   = (const float*)d_in[0];
    const float* Wq  = (const float*)d_in[1];
    const float* Wk  = (const float*)d_in[2];
    const float* Wv  = (const float*)d_in[3];
    const float* gq  = (const float*)d_in[4];
    const float* bq  = (const float*)d_in[5];
    const float* gv  = (const float*)d_in[6];
    const float* bv  = (const float*)d_in[7];
    const float* pos = (const float*)d_in[8];
    float* out = (float*)d_out;
    float* ws  = (float*)d_ws;

    float* qkv = ws;
    float* sA  = ws + 1441792;
    float* sB  = ws + 1441968;
    float* ksm = ws + 1442144;
    ushort16_t* qt_g = (ushort16_t*)(ws + 1573216);
    ushort16_t* vt_g = (ushort16_t*)(ws + 1835360);
    ushort16_t* lc_g = (ushort16_t*)(ws + 2228576);
    ushort16_t* xbf  = (ushort16_t*)(ws + 2240864);
    ushort16_t* wbf  = (ushort16_t*)(ws + 3813728);

    k_xt<<<dim3(260), dim3(256), 0, stream>>>(x, Wq, Wk, Wv, xbf, wbf);
    k_proj<<<dim3(128, 11), dim3(256), 0, stream>>>(xbf, wbf, qkv);
    k_bnsm<<<dim3(288), dim3(256), 0, stream>>>(qkv, gq, bq, gv, bv, sA, sB, ksm);
    k_packlc<<<dim3(1280), dim3(256), 0, stream>>>(qkv, sA, sB, ksm,
                                                   qt_g, vt_g, lc_g);
    k_main<<<dim3(128, 2), dim3(512), 0, stream>>>(pos, qt_g, vt_g, lc_g, out);
}

// Round 5
// 184.499 us; speedup vs baseline: 2.1690x; 1.0014x over previous
//
#include <hip/hip_runtime.h>

typedef __attribute__((ext_vector_type(8))) short short8;
typedef __attribute__((ext_vector_type(16))) float floatx16;
typedef __attribute__((ext_vector_type(4))) float floatx4;
typedef unsigned short ushort16_t;
typedef unsigned int uint32;

#define BB 8
#define CC 384
#define NPIX 1024
#define TOTCH 176      // 64 q + 16 k + 96 v
#define BN_EPS 1e-5f

// ---------- helpers ----------
__device__ __forceinline__ ushort16_t f2bf(float x) {
    uint32 u = __float_as_uint(x);
    u += 0x7FFFu + ((u >> 16) & 1u);
    return (ushort16_t)(u >> 16);
}
__device__ __forceinline__ uint32 pk2(float a, float b) {
    uint32 ua = __float_as_uint(a); ua += 0x7FFFu + ((ua >> 16) & 1u);
    uint32 ub = __float_as_uint(b); ub += 0x7FFFu + ((ub >> 16) & 1u);
    return (ua >> 16) | (ub & 0xFFFF0000u);
}
__device__ __forceinline__ void dma16(const ushort16_t* g, ushort16_t* l) {
    __builtin_amdgcn_global_load_lds(
        (const __attribute__((address_space(1))) uint32*)g,
        (__attribute__((address_space(3))) uint32*)l, 16, 0, 0);
}
__device__ __forceinline__ int div48(int x) {   // valid for x < 16384
    return (int)(((unsigned)x * 21846u) >> 20);
}

// ws layout (float units):
// qkv  [B][176][N]        @ 0         (1441792)
// sA   [176]              @ 1441792
// sB   [176]              @ 1441968
// ksm  [B][16][N]         @ 1442144   (131072)
// qt_g bf16 [n][kh2][bh32][8]                 @f 1573216 (262144 f)
// vt_g bf16 [b][mt32][vh2][vt3][mq4][v16][8]  @f 1835360 (393216 f)
// lc_g bf16 [b][vh2][vt3][mq4][v16][8]        @f 2228576 (12288 f)
// xbf  bf16 [col=b*1024+n][c384]              @f 2240864 (1572864 f)
// wbf  bf16 [row192][c384]                    @f 3813728 (36864 f)

// ---------------- K0: transpose x -> xbf via LDS; W -> wbf ------------------
__global__ __launch_bounds__(256) void k_xt(const float* __restrict__ x,
    const float* __restrict__ Wq, const float* __restrict__ Wk,
    const float* __restrict__ Wv,
    ushort16_t* __restrict__ xbf, ushort16_t* __restrict__ wbf)
{
    int bx = blockIdx.x, t = threadIdx.x;
    if (bx < 256) {
        // 32 cols x 384 c per block, bounced through LDS T[n][c]
        __shared__ __align__(16) ushort16_t T[32 * 392];  // pad c-stride to 392
        int col0 = bx * 32;
        int b = col0 >> 10, nbase = col0 & 1023;
        const float* xb = x + (size_t)b * (CC * NPIX) + nbase;
        #pragma unroll
        for (int j = 0; j < 12; ++j) {
            int idx = t + 256 * j;        // [0, 3072)
            int c = idx >> 3, ng = idx & 7;
            float4 f = *(const float4*)(xb + (size_t)c * NPIX + ng * 4);
            int n = ng * 4;
            T[(n + 0) * 392 + c] = f2bf(f.x);
            T[(n + 1) * 392 + c] = f2bf(f.y);
            T[(n + 2) * 392 + c] = f2bf(f.z);
            T[(n + 3) * 392 + c] = f2bf(f.w);
        }
        __syncthreads();
        #pragma unroll
        for (int j = 0; j < 6; ++j) {
            int task = t + 256 * j;       // [0, 1536) = 32 cols x 48 chunks
            int col = div48(task);
            int ch  = task - col * 48;
            uint4 w = *(const uint4*)&T[col * 392 + ch * 8];
            *(uint4*)&xbf[(size_t)(col0 + col) * CC + ch * 8] = w;
        }
    } else {
        // W conversion: 192 rows x 48 chunks of 8 = 9216 tasks over 4 blocks
        #pragma unroll
        for (int jj = 0; jj < 9; ++jj) {
            int idx8 = ((bx - 256) * 9 + jj) * 256 + t;   // [0, 9216)
            int row = div48(idx8);
            int g   = idx8 - row * 48;
            float4 f0, f1;
            if (row < 176) {
                const float* src;
                if (row < 64)       src = Wq + (size_t)row * CC;
                else if (row < 80)  src = Wk + (size_t)(row - 64) * CC;
                else                src = Wv + (size_t)(row - 80) * CC;
                f0 = *(const float4*)(src + g * 8);
                f1 = *(const float4*)(src + g * 8 + 4);
            } else {
                f0.x = f0.y = f0.z = f0.w = 0.f;
                f1 = f0;
            }
            uint4 w;
            w.x = pk2(f0.x, f0.y); w.y = pk2(f0.z, f0.w);
            w.z = pk2(f1.x, f1.y); w.w = pk2(f1.z, f1.w);
            *(uint4*)&wbf[(size_t)row * CC + g * 8] = w;
        }
    }
}

// ---------------- K1: q/k/v projection via MFMA (no LDS) --------------------
__global__ __launch_bounds__(256) void k_proj(const ushort16_t* __restrict__ xbf,
    const ushort16_t* __restrict__ wbf, float* __restrict__ qkv)
{
    int t = threadIdx.x;
    int wave = t >> 6, lane = t & 63;
    int ct = blockIdx.x * 4 + wave;       // col tile [0,512)
    int r0 = blockIdx.y * 16;             // row base (176 = 11*16 exact)
    int col = ct * 16 + (lane & 15);
    int kh  = lane >> 4;                  // 0..3 (k-half of 8)
    const ushort16_t* ap = wbf + (size_t)(r0 + (lane & 15)) * CC + kh * 8;
    const ushort16_t* bp = xbf + (size_t)col * CC + kh * 8;
    floatx4 acc = {0.f, 0.f, 0.f, 0.f};
    short8 a0 = *(const short8*)ap;
    short8 b0 = *(const short8*)bp;
    #pragma unroll
    for (int k = 1; k < 12; ++k) {
        short8 a1 = *(const short8*)(ap + k * 32);
        short8 b1 = *(const short8*)(bp + k * 32);
        acc = __builtin_amdgcn_mfma_f32_16x16x32_bf16(a0, b0, acc, 0, 0, 0);
        a0 = a1; b0 = b1;
    }
    acc = __builtin_amdgcn_mfma_f32_16x16x32_bf16(a0, b0, acc, 0, 0, 0);
    int b = col >> 10, n = col & 1023;
    #pragma unroll
    for (int r = 0; r < 4; ++r) {
        int ch = r0 + (lane >> 4) * 4 + r;
        qkv[((size_t)b * TOTCH + ch) * NPIX + n] = acc[r];
    }
}

// ---------------- K2: BN stats + softmax (merged, float4) -------------------
__global__ __launch_bounds__(256) void k_bnsm(const float* __restrict__ qkv,
    const float* __restrict__ gq, const float* __restrict__ bq,
    const float* __restrict__ gv, const float* __restrict__ bv,
    float* __restrict__ sA, float* __restrict__ sB, float* __restrict__ ksm)
{
    int bx = blockIdx.x, tid = threadIdx.x;
    int wid = tid >> 6, lane = tid & 63;
    if (bx < 160) {
        int ch = bx;
        int row; float gamma, beta;
        if (ch < 64) { row = ch; gamma = gq[ch]; beta = bq[ch]; }
        else { int j = ch - 64; row = 80 + j; gamma = gv[j]; beta = bv[j]; }
        float s = 0.f, ss = 0.f;
        #pragma unroll
        for (int j = 0; j < 8; ++j) {
            int i4 = tid + 256 * j;       // [0, 2048) float4s
            int b = i4 >> 8, n4 = i4 & 255;
            float4 f = *(const float4*)(qkv + ((size_t)b * TOTCH + row) * NPIX
                                            + n4 * 4);
            s  += f.x + f.y + f.z + f.w;
            ss += f.x * f.x + f.y * f.y + f.z * f.z + f.w * f.w;
        }
        #pragma unroll
        for (int off = 32; off > 0; off >>= 1) {
            s  += __shfl_down(s, off);
            ss += __shfl_down(ss, off);
        }
        __shared__ float rs[4], rss[4];
        if (lane == 0) { rs[wid] = s; rss[wid] = ss; }
        __syncthreads();
        if (tid == 0) {
            float S  = rs[0] + rs[1] + rs[2] + rs[3];
            float SS = rss[0] + rss[1] + rss[2] + rss[3];
            float inv = 1.f / (BB * NPIX);
            float mean = S * inv;
            float var  = SS * inv - mean * mean;
            float a = gamma * rsqrtf(var + BN_EPS);
            sA[row] = a;
            sB[row] = beta - mean * a;
        }
    } else {
        int idx = bx - 160;
        int kc = idx & 15, b = idx >> 4;
        const float* rowp = qkv + ((size_t)b * TOTCH + 64 + kc) * NPIX;
        float4 v4 = *(const float4*)(rowp + tid * 4);
        float v[4] = {v4.x, v4.y, v4.z, v4.w};
        float mx = fmaxf(fmaxf(v[0], v[1]), fmaxf(v[2], v[3]));
        #pragma unroll
        for (int off = 32; off > 0; off >>= 1) mx = fmaxf(mx, __shfl_down(mx, off));
        __shared__ float sm[4], ssum[4];
        if (lane == 0) sm[wid] = mx;
        __syncthreads();
        mx = fmaxf(fmaxf(sm[0], sm[1]), fmaxf(sm[2], sm[3]));
        float e[4], s = 0.f;
        #pragma unroll
        for (int j = 0; j < 4; ++j) { e[j] = __expf(v[j] - mx); s += e[j]; }
        #pragma unroll
        for (int off = 32; off > 0; off >>= 1) s += __shfl_down(s, off);
        if (lane == 0) ssum[wid] = s;
        __syncthreads();
        float inv = 1.f / (ssum[0] + ssum[1] + ssum[2] + ssum[3]);
        float4 o;
        o.x = e[0] * inv; o.y = e[1] * inv; o.z = e[2] * inv; o.w = e[3] * inv;
        *(float4*)(ksm + ((size_t)b * 16 + kc) * NPIX + tid * 4) = o;
    }
}

// ---------------- K3: pack q/v (bf16 tiled) + content lambda (fused) --------
__global__ __launch_bounds__(256) void k_packlc(const float* __restrict__ qkv,
    const float* __restrict__ sA, const float* __restrict__ sB,
    const float* __restrict__ ksm,
    ushort16_t* __restrict__ qt_g, ushort16_t* __restrict__ vt_g,
    ushort16_t* __restrict__ lc_g)
{
    int bx = blockIdx.x, t = threadIdx.x;
    if (bx < 128) {
        // q part: qt_g[n][kh][bh][8]; one (n, bh) per thread
        int bh = t & 31, nn = (t >> 5) & 7;
        int n = bx * 8 + nn;
        int b = bh >> 2, h = bh & 3;
        float vals[16];
        #pragma unroll
        for (int k = 0; k < 16; ++k) {
            int ch = h * 16 + k;
            vals[k] = qkv[((size_t)b * TOTCH + ch) * NPIX + n] * sA[ch] + sB[ch];
        }
        uint4 w0, w1;
        w0.x = pk2(vals[0], vals[1]);  w0.y = pk2(vals[2], vals[3]);
        w0.z = pk2(vals[4], vals[5]);  w0.w = pk2(vals[6], vals[7]);
        w1.x = pk2(vals[8], vals[9]);  w1.y = pk2(vals[10], vals[11]);
        w1.z = pk2(vals[12], vals[13]); w1.w = pk2(vals[14], vals[15]);
        *(uint4*)&qt_g[(size_t)n * 512 + bh * 8]       = w0;
        *(uint4*)&qt_g[(size_t)n * 512 + 256 + bh * 8] = w1;
    } else if (bx < 512) {
        // v part: vt_g[b][mt][vh][vt][mq][vl][8]
        int gi = (bx - 128) * 256 + t;   // < 98304
        int m8 = gi & 127;
        int vg = (gi >> 7) % 96;
        int b  = gi / (96 * 128);
        int m  = m8 * 8;
        int row = 80 + vg;
        float a = sA[row], bb = sB[row];
        const float* p = qkv + ((size_t)b * TOTCH + row) * NPIX + m;
        float4 f0 = *(const float4*)p;
        float4 f1 = *(const float4*)(p + 4);
        uint4 w;
        w.x = pk2(f0.x * a + bb, f0.y * a + bb);
        w.y = pk2(f0.z * a + bb, f0.w * a + bb);
        w.z = pk2(f1.x * a + bb, f1.y * a + bb);
        w.w = pk2(f1.z * a + bb, f1.w * a + bb);
        int mt = m >> 5, mq = (m >> 3) & 3;
        int vhh = vg / 48, vtt = (vg % 48) >> 4, vl = vg & 15;
        size_t idx = ((((size_t)b * 32 + mt) * 2 + vhh) * 3 + vtt) * 512
                   + mq * 128 + vl * 8;
        *(uint4*)&vt_g[idx] = w;
    } else {
        // content lambda
        int gi = bx - 512;
        int v = gi % 96, b = gi / 96;
        int row = 80 + v;
        float a = sA[row], bb = sB[row];
        const float* vp = qkv + ((size_t)b * TOTCH + row) * NPIX;
        const float* kp = ksm + (size_t)b * 16 * NPIX;
        float acc[16];
        #pragma unroll
        for (int k = 0; k < 16; ++k) acc[k] = 0.f;
        for (int m = t; m < NPIX; m += 256) {
            float vv = vp[m] * a + bb;
            #pragma unroll
            for (int k = 0; k < 16; ++k) acc[k] += kp[k * NPIX + m] * vv;
        }
        #pragma unroll
        for (int k = 0; k < 16; ++k) {
            #pragma unroll
            for (int off = 32; off > 0; off >>= 1)
                acc[k] += __shfl_down(acc[k], off);
        }
        __shared__ float red[16][4];
        int wid = t >> 6, lane = t & 63;
        if (lane == 0) {
            #pragma unroll
            for (int k = 0; k < 16; ++k) red[k][wid] = acc[k];
        }
        __syncthreads();
        int vhh = v / 48, vtt = (v % 48) >> 4, vl = v & 15;
        size_t plane = ((size_t)(b * 2 + vhh) * 3 + vtt) * 512;
        if (t < 16) {
            int k = t;
            float val = red[k][0] + red[k][1] + red[k][2] + red[k][3];
            lc_g[plane + (k >> 3) * 128 + vl * 8 + (k & 7)] = f2bf(val);
        } else if (t < 18) {
            int mq = 2 + (t - 16);
            uint4 z; z.x = z.y = z.z = z.w = 0u;
            *(uint4*)&lc_g[plane + mq * 128 + vl * 8] = z;
        }
    }
}

// ---------------- K4: fused MFMA position+content lambda (1 barrier/iter) ---
// grid (128 n-tiles of 8, 2 v-halves), 512 threads (8 waves).
// A-frag (P) loaded DIRECTLY from pos to regs (no LDS staging); S_s double-
// buffered so only ONE barrier per iteration; V dma issued right after the
// barrier -> drained at the NEXT barrier, a full iteration later.
__global__ __launch_bounds__(512, 2) void k_main(const float* __restrict__ pos,
    const ushort16_t* __restrict__ qt_g, const ushort16_t* __restrict__ vt_g,
    const ushort16_t* __restrict__ lc_g, float* __restrict__ out)
{
    __shared__ __align__(16) ushort16_t V_s[2][12288];  // 48 KB [b8][vt3][mq4][v16][8]
    __shared__ __align__(16) ushort16_t S_s[2][8192];   // 32 KB [plane16][chunk64][8]
    int tid  = threadIdx.x;
    int lane = tid & 63;
    int wave = tid >> 6;          // phase-1: n index; phase-2: b index
    int n0 = blockIdx.x * 8;
    int vh = blockIdx.y;

    int col1 = lane & 31, half = lane >> 5;
    int pb = col1 >> 2, ph = col1 & 3;
    int pplane = pb * 2 + (ph >> 1);
    int pf = pplane & 7;
    int pcb = ph & 1;
    int b2 = wave;

    // q fragment: one short8 per lane, fixed for whole kernel
    short8 qfr = *(const short8*)(qt_g + (size_t)(n0 + wave) * 512
                                  + half * 256 + col1 * 8);

    floatx4 acc[2][3];
    #pragma unroll
    for (int hg = 0; hg < 2; ++hg)
        #pragma unroll
        for (int vt = 0; vt < 3; ++vt)
            acc[hg][vt] = floatx4{0.f, 0.f, 0.f, 0.f};

    floatx16 z16;
    #pragma unroll
    for (int i = 0; i < 16; ++i) z16[i] = 0.f;

    // lane's A-frag source: P[n=n0+wave][m=col1][k=half*8 .. +8], fp32
    const float* pA = pos + ((size_t)(n0 + wave) * 1024 + col1) * 16 + half * 8;

    // ---- prologue: A(0) regs, dma V(0) ----
    float4 a0 = *(const float4*)pA;
    float4 a1 = *(const float4*)(pA + 4);
    {
        const ushort16_t* src = vt_g + (size_t)((b2 * 32 * 2 + vh) * 3) * 512;
        #pragma unroll
        for (int j = 0; j < 3; ++j)
            dma16(src + j * 512 + lane * 8, &V_s[0][b2 * 1536 + j * 512]);
    }

    for (int it = 0; it < 32; ++it) {
        // prefetch A(it+1) regs (drained at this iter's barrier)
        float4 na0, na1;
        if (it < 31) {
            const float* p = pA + (size_t)(it + 1) * 512;
            na0 = *(const float4*)p;
            na1 = *(const float4*)(p + 4);
        }
        // phase-1 (n = wave): S = P * q
        {
            uint4 aw;
            aw.x = pk2(a0.x, a0.y); aw.y = pk2(a0.z, a0.w);
            aw.z = pk2(a1.x, a1.y); aw.w = pk2(a1.z, a1.w);
            short8 afr = *(short8*)&aw;
            floatx16 d = __builtin_amdgcn_mfma_f32_32x32x16_bf16(
                afr, qfr, z16, 0, 0, 0);
            int nx = wave ^ pf;
            ushort16_t* Sb = S_s[it & 1];
            #pragma unroll
            for (int q = 0; q < 4; ++q) {
                int c = q * 16 + pcb * 8 + nx;
                uint2 wv;
                wv.x = pk2(d[q * 4 + 0], d[q * 4 + 1]);
                wv.y = pk2(d[q * 4 + 2], d[q * 4 + 3]);
                *(uint2*)&Sb[pplane * 512 + c * 8 + half * 4] = wv;
            }
        }
        __syncthreads();   // THE one barrier: S(it) visible; drains A-prefetch + V dma(it)
        // dma V(it+1) right after barrier -> drains at NEXT barrier
        if (it < 31) {
            const ushort16_t* src = vt_g
                + (size_t)(((b2 * 32 + it + 1) * 2 + vh) * 3) * 512;
            #pragma unroll
            for (int j = 0; j < 3; ++j)
                dma16(src + j * 512 + lane * 8,
                      &V_s[(it + 1) & 1][b2 * 1536 + j * 512]);
        }
        // phase-2 (b = wave): acc += V * S
        {
            const ushort16_t* Vb = V_s[it & 1];
            const ushort16_t* Sb = S_s[it & 1];
            short8 av[3];
            #pragma unroll
            for (int vt = 0; vt < 3; ++vt)
                av[vt] = *(const short8*)&Vb[b2 * 1536 + vt * 512 + lane * 8];
            #pragma unroll
            for (int hg = 0; hg < 2; ++hg) {
                int p2 = b2 * 2 + hg, f2 = p2 & 7;
                short8 bs = *(const short8*)&Sb[p2 * 512
                    + ((lane >> 4) * 16 + ((lane & 15) ^ f2)) * 8];
                #pragma unroll
                for (int vt = 0; vt < 3; ++vt)
                    acc[hg][vt] = __builtin_amdgcn_mfma_f32_16x16x32_bf16(
                        av[vt], bs, acc[hg][vt], 0, 0, 0);
            }
        }
        a0 = na0; a1 = na1;
    }

    // ---- content-lambda extension (uses buffers [0]; safe: all waves are
    // past barrier(31), so phase-2(30) reads of [0] are complete) ----
    {
        const ushort16_t* src = lc_g + (size_t)((b2 * 2 + vh) * 3) * 512;
        #pragma unroll
        for (int j = 0; j < 3; ++j)
            dma16(src + j * 512 + lane * 8, &V_s[0][b2 * 1536 + j * 512]);
    }
    {
        int c = half * 16 + pcb * 8 + (wave ^ pf);
        *(short8*)&S_s[0][pplane * 512 + c * 8] = qfr;
        int zp = tid >> 5, zr = tid & 31;
        int zc = (2 + (zr >> 4)) * 16 + ((zr & 15) ^ (zp & 7));
        uint4 z; z.x = z.y = z.z = z.w = 0u;
        *(uint4*)&S_s[0][zp * 512 + zc * 8] = z;
    }
    __syncthreads();
    {
        short8 av[3];
        #pragma unroll
        for (int vt = 0; vt < 3; ++vt)
            av[vt] = *(const short8*)&V_s[0][b2 * 1536 + vt * 512 + lane * 8];
        #pragma unroll
        for (int hg = 0; hg < 2; ++hg) {
            int p2 = b2 * 2 + hg, f2 = p2 & 7;
            short8 bs = *(const short8*)&S_s[0][p2 * 512
                + ((lane >> 4) * 16 + ((lane & 15) ^ f2)) * 8];
            #pragma unroll
            for (int vt = 0; vt < 3; ++vt)
                acc[hg][vt] = __builtin_amdgcn_mfma_f32_16x16x32_bf16(
                    av[vt], bs, acc[hg][vt], 0, 0, 0);
        }
    }

    // ---- epilogue ----
    {
        int cn = lane & 15;
        int nloc = cn & 7;
        #pragma unroll
        for (int hg = 0; hg < 2; ++hg) {
            int h = hg * 2 + (cn >> 3);
            #pragma unroll
            for (int vt = 0; vt < 3; ++vt) {
                #pragma unroll
                for (int r = 0; r < 4; ++r) {
                    int v = vh * 48 + vt * 16 + (lane >> 4) * 4 + r;
                    out[(size_t)(b2 * 384 + h * 96 + v) * 1024 + n0 + nloc]
                        = acc[hg][vt][r];
                }
            }
        }
    }
}

extern "C" void kernel_launch(void* const* d_in, const int* in_sizes, int n_in,
                              void* d_out, int out_size, void* d_ws, size_t ws_size,
                              hipStream_t stream) {
    const float* x   = (const float*)d_in[0];
    const float* Wq  = (const float*)d_in[1];
    const float* Wk  = (const float*)d_in[2];
    const float* Wv  = (const float*)d_in[3];
    const float* gq  = (const float*)d_in[4];
    const float* bq  = (const float*)d_in[5];
    const float* gv  = (const float*)d_in[6];
    const float* bv  = (const float*)d_in[7];
    const float* pos = (const float*)d_in[8];
    float* out = (float*)d_out;
    float* ws  = (float*)d_ws;

    float* qkv = ws;
    float* sA  = ws + 1441792;
    float* sB  = ws + 1441968;
    float* ksm = ws + 1442144;
    ushort16_t* qt_g = (ushort16_t*)(ws + 1573216);
    ushort16_t* vt_g = (ushort16_t*)(ws + 1835360);
    ushort16_t* lc_g = (ushort16_t*)(ws + 2228576);
    ushort16_t* xbf  = (ushort16_t*)(ws + 2240864);
    ushort16_t* wbf  = (ushort16_t*)(ws + 3813728);

    k_xt<<<dim3(260), dim3(256), 0, stream>>>(x, Wq, Wk, Wv, xbf, wbf);
    k_proj<<<dim3(128, 11), dim3(256), 0, stream>>>(xbf, wbf, qkv);
    k_bnsm<<<dim3(288), dim3(256), 0, stream>>>(qkv, gq, bq, gv, bv, sA, sB, ksm);
    k_packlc<<<dim3(1280), dim3(256), 0, stream>>>(qkv, sA, sB, ksm,
                                                   qt_g, vt_g, lc_g);
    k_main<<<dim3(128, 2), dim3(512), 0, stream>>>(pos, qt_g, vt_g, lc_g, out);
}